// Round 9
// baseline (3866.620 us; speedup 1.0000x reference)
//
#include <hip/hip_runtime.h>
#include <hip/hip_bf16.h>

// BitNet 4-layer MLP forward, MI355X — round 9: gemm2p at 2 blocks/CU.
// r3-r8 ledger: sync count, bank conflicts, staged bytes, MFMA issue rate all
// refuted; every 256^2 variant shares a ~6000cy/K-tile fixed stall AND
// 1 block/CU. Fix: LDS 82432 -> 81920 (B-pad dropped, parity-XOR banking)
// so two independent blocks co-reside per CU and overlap each other's stalls.

typedef __attribute__((ext_vector_type(4))) int i32x4_t;

#define GLDS16(g, l) __builtin_amdgcn_global_load_lds( \
    (const __attribute__((address_space(1))) unsigned int*)(g), \
    (__attribute__((address_space(3))) unsigned int*)(l), 16, 0, 0)

static __device__ __forceinline__ unsigned char f2i8(float f) {
  return (unsigned char)(int)f;   // f already rint'ed and clipped
}

// ---------------- weight abs-mean (deterministic two-stage fp64) ------------
__global__ __launch_bounds__(256) void absmean_part_k(
    const float* __restrict__ W, int n4, double* __restrict__ part)
{
  double s = 0.0;
  const int stride = gridDim.x * 256;
  for (int i = blockIdx.x * 256 + threadIdx.x; i < n4; i += stride) {
    float4 v = ((const float4*)W)[i];
    s += (double)fabsf(v.x); s += (double)fabsf(v.y);
    s += (double)fabsf(v.z); s += (double)fabsf(v.w);
  }
  __shared__ double sd[256];
  sd[threadIdx.x] = s;
  __syncthreads();
  for (int st = 128; st > 0; st >>= 1) {
    if (threadIdx.x < st) sd[threadIdx.x] += sd[threadIdx.x + st];
    __syncthreads();
  }
  if (threadIdx.x == 0) part[blockIdx.x] = sd[0];
}

__global__ __launch_bounds__(256) void absmean_fin_k(
    const double* __restrict__ part, int nPart, double n,
    float* __restrict__ wsc, int widx)
{
  __shared__ double sd[256];
  double s = 0.0;
  for (int i = threadIdx.x; i < nPart; i += 256) s += part[i];
  sd[threadIdx.x] = s;
  __syncthreads();
  for (int st = 128; st > 0; st >>= 1) {
    if (threadIdx.x < st) sd[threadIdx.x] += sd[threadIdx.x + st];
    __syncthreads();
  }
  if (threadIdx.x == 0) {
    float mean = (float)(sd[0] / n);
    float scale = 1.f / fmaxf(mean, 1e-5f);
    wsc[widx * 2]     = scale;
    wsc[widx * 2 + 1] = 1.f / scale;
  }
}

// ---------------- weight ternary quantization to i8 {-1,0,1} (w1, w4) -------
__global__ __launch_bounds__(256) void quant_w_k(
    const float* __restrict__ W, unsigned int* __restrict__ Wq,
    const float* __restrict__ wsc, int widx, int n4)
{
  const float s = wsc[widx * 2];
  const int stride = gridDim.x * 256;
  for (int i = blockIdx.x * 256 + threadIdx.x; i < n4; i += stride) {
    float4 v = ((const float4*)W)[i];
    unsigned int u =
        (unsigned int)f2i8(fminf(fmaxf(rintf(v.x * s), -1.f), 1.f)) |
        ((unsigned int)f2i8(fminf(fmaxf(rintf(v.y * s), -1.f), 1.f)) << 8) |
        ((unsigned int)f2i8(fminf(fmaxf(rintf(v.z * s), -1.f), 1.f)) << 16) |
        ((unsigned int)f2i8(fminf(fmaxf(rintf(v.w * s), -1.f), 1.f)) << 24);
    Wq[i] = u;
  }
}

// ---------------- weight ternary quantization to 2-bit packed (w2, w3) ------
// Wp[kc][o], kc = k/16; crumb for k = kc*16 + (m + 4*j) at byte m, bits 2j.
// Unpack dword j = (u >> 2j) & 0x03030303 -> byte m = k 4j+m (k-ascending).
__global__ __launch_bounds__(256) void quant_w_pack_k(
    const float* __restrict__ W, unsigned int* __restrict__ Wp,
    const float* __restrict__ wsc, int widx, int Kd, int Nd)
{
  const float s = wsc[widx * 2];
  const int idx = blockIdx.x * 256 + threadIdx.x;
  const int kc = idx & (Kd / 16 - 1);
  const int o  = idx / (Kd / 16);
  if (o >= Nd) return;
  const float* wr = W + (size_t)o * Kd + kc * 16;
  unsigned int u = 0;
  #pragma unroll
  for (int e = 0; e < 16; ++e) {
    int q = (int)fminf(fmaxf(rintf(wr[e] * s), -1.f), 1.f);
    u |= (unsigned int)(q & 3) << (8 * (e & 3) + 2 * (e >> 2));
  }
  Wp[(size_t)kc * Nd + o] = u;
}

// ---------------- per-row activation quantization to i8 ---------------------
template<int D>
__global__ __launch_bounds__(256) void act_quant_k(
    const float* __restrict__ X, unsigned int* __restrict__ Xq,
    float* __restrict__ inv_sa)
{
  constexpr int PER = D / 1024;
  const int row = blockIdx.x, tid = threadIdx.x;
  const float4* xr = (const float4*)(X + (size_t)row * D);
  float4 v[PER];
  float m = 0.f;
  #pragma unroll
  for (int i = 0; i < PER; ++i) {
    v[i] = xr[tid + 256 * i];
    m = fmaxf(m, fmaxf(fmaxf(fabsf(v[i].x), fabsf(v[i].y)),
                       fmaxf(fabsf(v[i].z), fabsf(v[i].w))));
  }
  #pragma unroll
  for (int off = 32; off >= 1; off >>= 1) m = fmaxf(m, __shfl_xor(m, off));
  __shared__ float wm[4];
  if ((tid & 63) == 0) wm[tid >> 6] = m;
  __syncthreads();
  m = fmaxf(fmaxf(wm[0], wm[1]), fmaxf(wm[2], wm[3]));
  const float s = 127.f / fmaxf(m, 1e-5f);
  if (tid == 0) inv_sa[row] = 1.f / s;
  unsigned int* oq = Xq + (size_t)row * (D / 4);
  #pragma unroll
  for (int i = 0; i < PER; ++i) {
    unsigned int u =
        (unsigned int)f2i8(fminf(fmaxf(rintf(v[i].x * s), -128.f), 127.f)) |
        ((unsigned int)f2i8(fminf(fmaxf(rintf(v[i].y * s), -128.f), 127.f)) << 8) |
        ((unsigned int)f2i8(fminf(fmaxf(rintf(v[i].z * s), -128.f), 127.f)) << 16) |
        ((unsigned int)f2i8(fminf(fmaxf(rintf(v[i].w * s), -128.f), 127.f)) << 24);
    oq[tid + 256 * i] = u;
  }
}

// ---------------- 128^2 2-phase i8 GEMM (proven; used for L1/L4) ------------
template<int K, int N, bool TANH>
__global__ __launch_bounds__(256) void gemm_bt(
    const signed char* __restrict__ A, const signed char* __restrict__ W,
    const float* __restrict__ inv_sa, const float* __restrict__ wsc, int widx,
    const float* __restrict__ bias, float* __restrict__ out)
{
  __shared__ __align__(16) signed char As[128 * 64];
  __shared__ __align__(16) signed char Bs[128 * 64];
  const int tid = threadIdx.x;
  const int wv = tid >> 6, ln = tid & 63;
  const int bm = blockIdx.y, bn = blockIdx.x;
  const int wr = wv >> 1, wc = wv & 1;
  const signed char* Ab = A + (size_t)bm * 128 * K;
  const signed char* Wb = W + (size_t)bn * 128 * K;
  i32x4_t acc[4][4];
  #pragma unroll
  for (int m = 0; m < 4; ++m)
    #pragma unroll
    for (int n = 0; n < 4; ++n) acc[m][n] = (i32x4_t){0, 0, 0, 0};

  for (int k0 = 0; k0 < K; k0 += 64) {
    #pragma unroll
    for (int l = 0; l < 2; ++l) {
      const int c = l * 256 + wv * 64 + ln;
      const int row = c >> 2;
      const int kc = (c & 3) * 16;
      GLDS16(Ab + (size_t)row * K + k0 + kc, As + (l * 256 + wv * 64) * 16);
      GLDS16(Wb + (size_t)row * K + k0 + kc, Bs + (l * 256 + wv * 64) * 16);
    }
    __syncthreads();
    i32x4_t aw[4], bw[4];
    #pragma unroll
    for (int m = 0; m < 4; ++m)
      aw[m] = *(const i32x4_t*)(As + (wr * 64 + m * 16 + (ln & 15)) * 64 + (ln >> 4) * 16);
    #pragma unroll
    for (int n = 0; n < 4; ++n)
      bw[n] = *(const i32x4_t*)(Bs + (wc * 64 + n * 16 + (ln & 15)) * 64 + (ln >> 4) * 16);
    #pragma unroll
    for (int m = 0; m < 4; ++m)
      #pragma unroll
      for (int n = 0; n < 4; ++n)
        acc[m][n] = __builtin_amdgcn_mfma_i32_16x16x64_i8(aw[m], bw[n], acc[m][n], 0, 0, 0);
    __syncthreads();
  }

  const float invw = wsc[widx * 2 + 1];
  #pragma unroll
  for (int m = 0; m < 4; ++m) {
    const int gb0 = bm * 128 + wr * 64 + m * 16 + ((ln >> 4) << 2);
    #pragma unroll
    for (int r = 0; r < 4; ++r) {
      const int gb = gb0 + r;
      const float fa = inv_sa[gb] * invw;
      #pragma unroll
      for (int n = 0; n < 4; ++n) {
        const int go = bn * 128 + wc * 64 + n * 16 + (ln & 15);
        const float v = (float)acc[m][n][r] * fa + bias[go];
        out[(size_t)gb * N + go] = TANH ? tanhf(v) : v;
      }
    }
  }
}

// ---------------- 256^2 dbuf i8xA / 2-bit-B GEMM, 2 blocks/CU (L2/L3) -------
// BM=BN=256, BK=128. 8 waves (2M x 4N), per-wave output 128x64.
// LDS per buffer: A 32KB (3-bit XOR swizzle) + B 8192B packed 2-bit, 8 slices
// of 1KB; slice kc stores global col c at pos c ^ ((kc&1)<<4) (parity XOR ->
// 2-way banks = free, no pad needed). Block LDS = 2*40960 = 81920 B exactly
// -> 2 blocks/CU. launch_bounds(512,4) pins VGPR <= 128 for 16 waves/CU.
template<int K, int N, bool TANH>
__global__ __launch_bounds__(512, 4) void gemm2p(
    const signed char* __restrict__ A, const unsigned int* __restrict__ Wp,
    const float* __restrict__ inv_sa, const float* __restrict__ wsc, int widx,
    const float* __restrict__ bias, float* __restrict__ out)
{
  constexpr int BUFSZ = 32768 + 8192;               // 40960 B per buffer
  __shared__ __align__(16) signed char lds[2 * BUFSZ];
  constexpr int NT = K / 128;
  const int tid = threadIdx.x;
  const int wv = tid >> 6, ln = tid & 63;
  const int wr = wv >> 2, wc = wv & 3;              // 2 x 4 wave grid
  const int g = ln >> 4, rl = ln & 15;
  const int colswz = (rl & 7) << 4;                 // A read-side 3-bit XOR

  // XCD-aware block swizzle (nwg % 8 == 0 for all our grids)
  const int nwg = gridDim.x * gridDim.y;
  int lbid = blockIdx.y * gridDim.x + blockIdx.x;
  lbid = (lbid & 7) * (nwg >> 3) + (lbid >> 3);
  const int bn = lbid % gridDim.x, bm = lbid / gridDim.x;

  const signed char* Abase = A + (size_t)bm * 256 * K;
  const unsigned int* Wpb = Wp + (size_t)bn * 256;  // [kc][N] cols bn*256..

  // A staging: LDS chunk c (linear dest) <- global chunk c ^ ((c>>3)&7).
  // B staging: wave kc=tid>>6 stages its 1KB slice; source col pre-XOR'd by
  // slice parity so LDS[kc][p] = G[kc][p ^ ((kc&1)<<4)].
  auto stage = [&](int tt) {
    if (tt >= NT) return;
    signed char* dA = lds + (tt & 1) * BUFSZ;
    #pragma unroll
    for (int i = 0; i < 4; ++i) {
      const int c = tid + 512 * i;
      GLDS16(Abase + (size_t)(c >> 3) * K + tt * 128 + ((c ^ (c >> 3)) & 7) * 16,
             dA + c * 16);
    }
    const int kc = tid >> 6;
    const int sw = ((tid & 63) * 4) ^ ((kc & 1) << 4);   // dword index
    GLDS16(Wpb + (size_t)(tt * 8 + kc) * N + sw,
           dA + 32768 + kc * 1024 + (tid & 63) * 16);
  };

  i32x4_t acc[8][4];
  #pragma unroll
  for (int m = 0; m < 8; ++m)
    #pragma unroll
    for (int n = 0; n < 4; ++n) acc[m][n] = (i32x4_t){0, 0, 0, 0};

  const int myAoff = wr * 16384;
  const int bcol = wc * 64;                         // this wave's B col base

  // prologue
  stage(0); stage(1);
  if (NT > 1) asm volatile("s_waitcnt vmcnt(5)" ::: "memory");
  else        asm volatile("s_waitcnt vmcnt(0)" ::: "memory");
  __builtin_amdgcn_s_barrier();

  for (int t = 0; t < NT; ++t) {
    const signed char* base = lds + (t & 1) * BUFSZ;
    const signed char* mA = base + myAoff;
    const unsigned int* mB = (const unsigned int*)(base + 32768);

    // B: 8 x b32 packed reads (parity-XOR position), unpack to k-order dwords
    i32x4_t bfr[4][2];
    #pragma unroll
    for (int n = 0; n < 4; ++n)
      #pragma unroll
      for (int ks = 0; ks < 2; ++ks) {
        const unsigned int u = mB[(ks * 4 + g) * 256
                                  + ((bcol + n * 16 + rl) ^ ((g & 1) << 4))];
        #pragma unroll
        for (int j = 0; j < 4; ++j) {
          unsigned int tj = (u >> (2 * j)) & 0x03030303u;
          bfr[n][ks][j] = (int)(tj | ((tj & 0x02020202u) * 0x7Fu));
        }
      }

    // A: 16 x b128 reads
    i32x4_t afr[8][2];
    #pragma unroll
    for (int m = 0; m < 8; ++m)
      #pragma unroll
      for (int ks = 0; ks < 2; ++ks)
        afr[m][ks] = *(const i32x4_t*)(mA + (m * 16 + rl) * 128
                                       + ((ks * 64 + g * 16) ^ colswz));

    __builtin_amdgcn_s_setprio(1);
    #pragma unroll
    for (int ks = 0; ks < 2; ++ks)       // ks-outer: no back-to-back acc deps
      #pragma unroll
      for (int m = 0; m < 8; ++m)
        #pragma unroll
        for (int n = 0; n < 4; ++n)
          acc[m][n] = __builtin_amdgcn_mfma_i32_16x16x64_i8(
              afr[m][ks], bfr[n][ks], acc[m][n], 0, 0, 0);
    __builtin_amdgcn_s_setprio(0);

    asm volatile("s_waitcnt lgkmcnt(0)" ::: "memory");
    __builtin_amdgcn_s_barrier();            // all waves done reading buf[cur]
    stage(t + 2);                            // refill buf[cur] with tile t+2
    if (t + 2 < NT) asm volatile("s_waitcnt vmcnt(5)" ::: "memory");
    else            asm volatile("s_waitcnt vmcnt(0)" ::: "memory");
    __builtin_amdgcn_s_barrier();            // tile t+1 confirmed resident
  }

  // -------- epilogue --------
  const float invw = wsc[widx * 2 + 1];
  const int row0 = bm * 256 + wr * 128;
  const int col0 = bn * 256 + wc * 64;
  #pragma unroll
  for (int m = 0; m < 8; ++m) {
    #pragma unroll
    for (int r = 0; r < 4; ++r) {
      const int gb = row0 + m * 16 + g * 4 + r;
      const float fa = inv_sa[gb] * invw;
      #pragma unroll
      for (int n = 0; n < 4; ++n) {
        const int go = col0 + n * 16 + rl;
        const float v = (float)acc[m][n][r] * fa + bias[go];
        out[(size_t)gb * N + go] = TANH ? tanhf(v) : v;
      }
    }
  }
}

// ---------------- driver ----------------------------------------------------
extern "C" void kernel_launch(void* const* d_in, const int* in_sizes, int n_in,
                              void* d_out, int out_size, void* d_ws, size_t ws_size,
                              hipStream_t stream)
{
  const float* x  = (const float*)d_in[0];
  const float* w1 = (const float*)d_in[1]; const float* b1 = (const float*)d_in[2];
  const float* w2 = (const float*)d_in[3]; const float* b2 = (const float*)d_in[4];
  const float* w3 = (const float*)d_in[5]; const float* b3 = (const float*)d_in[6];
  const float* w4 = (const float*)d_in[7]; const float* b4 = (const float*)d_in[8];
  float* out = (float*)d_out;

  constexpr int B = 8192, DIN = 1024, H = 4096, DOUT = 1024;
  char* ws = (char*)d_ws;
  size_t off = 0;
  float*        hbuf = (float*)(ws + off);        off += (size_t)B * H * 4;
  signed char*  xq   = (signed char*)(ws + off);  off += (size_t)B * H;
  signed char*  wq   = (signed char*)(ws + off);  off += (size_t)H * H;     // i8 (w1/w4)
  unsigned int* wp2  = (unsigned int*)(ws + off); off += (size_t)(H / 16) * H * 4;
  unsigned int* wp3  = (unsigned int*)(ws + off); off += (size_t)(H / 16) * H * 4;
  float*        inv_sa = (float*)(ws + off);      off += (size_t)B * 4;
  double*       part = (double*)(ws + off);       off += 1024 * 8;
  float*        wsc  = (float*)(ws + off);        off += 64;

  absmean_part_k<<<1024, 256, 0, stream>>>(w1, H * DIN / 4, part);
  absmean_fin_k<<<1, 256, 0, stream>>>(part, 1024, (double)H * DIN, wsc, 0);
  absmean_part_k<<<1024, 256, 0, stream>>>(w2, H * H / 4, part);
  absmean_fin_k<<<1, 256, 0, stream>>>(part, 1024, (double)H * H, wsc, 1);
  absmean_part_k<<<1024, 256, 0, stream>>>(w3, H * H / 4, part);
  absmean_fin_k<<<1, 256, 0, stream>>>(part, 1024, (double)H * H, wsc, 2);
  absmean_part_k<<<1024, 256, 0, stream>>>(w4, DOUT * H / 4, part);
  absmean_fin_k<<<1, 256, 0, stream>>>(part, 1024, (double)DOUT * H, wsc, 3);

  // layer 1 (K=1024): 128^2 i8 kernel
  act_quant_k<DIN><<<B, 256, 0, stream>>>(x, (unsigned int*)xq, inv_sa);
  quant_w_k<<<2048, 256, 0, stream>>>(w1, (unsigned int*)wq, wsc, 0, H * DIN / 4);
  gemm_bt<DIN, H, true><<<dim3(H / 128, B / 128), 256, 0, stream>>>(
      xq, wq, inv_sa, wsc, 0, b1, hbuf);

  // layer 2: 256^2 packed-B, 2 blocks/CU
  act_quant_k<H><<<B, 256, 0, stream>>>(hbuf, (unsigned int*)xq, inv_sa);
  quant_w_pack_k<<<(H / 16) * H / 256, 256, 0, stream>>>(w2, wp2, wsc, 1, H, H);
  gemm2p<H, H, true><<<dim3(H / 256, B / 256), 512, 0, stream>>>(
      xq, wp2, inv_sa, wsc, 1, b2, hbuf);

  // layer 3: 256^2 packed-B, 2 blocks/CU
  act_quant_k<H><<<B, 256, 0, stream>>>(hbuf, (unsigned int*)xq, inv_sa);
  quant_w_pack_k<<<(H / 16) * H / 256, 256, 0, stream>>>(w3, wp3, wsc, 2, H, H);
  gemm2p<H, H, true><<<dim3(H / 256, B / 256), 512, 0, stream>>>(
      xq, wp3, inv_sa, wsc, 2, b3, hbuf);

  // layer 4 (N=1024): 128^2 i8 kernel
  act_quant_k<H><<<B, 256, 0, stream>>>(hbuf, (unsigned int*)xq, inv_sa);
  quant_w_k<<<2048, 256, 0, stream>>>(w4, (unsigned int*)wq, wsc, 3, DOUT * H / 4);
  gemm_bt<H, DOUT, false><<<dim3(DOUT / 128, B / 128), 256, 0, stream>>>(
      xq, wq, inv_sa, wsc, 3, b4, out);
}

// Round 10
// 594.339 us; speedup vs baseline: 6.5057x; 6.5057x over previous
//
#include <hip/hip_runtime.h>
#include <hip/hip_bf16.h>

// BitNet 4-layer MLP forward, MI355X — round 10: CLEAN 2-blocks/CU test.
// r9 spilled (acc alone = 128 regs at 256^2). New L2/L3 tile: 256x128,
// 8 waves (4Mx2N), per-wave 64x64 -> acc 64 AGPR; ks-outer loop keeps arch
// VGPR ~64. LDS/buf = A 32KB + B-packed 512B*8 = 36KB; dbuf 72KB -> 2 blocks.

typedef __attribute__((ext_vector_type(4))) int i32x4_t;

#define GLDS16(g, l) __builtin_amdgcn_global_load_lds( \
    (const __attribute__((address_space(1))) unsigned int*)(g), \
    (__attribute__((address_space(3))) unsigned int*)(l), 16, 0, 0)

static __device__ __forceinline__ unsigned char f2i8(float f) {
  return (unsigned char)(int)f;   // f already rint'ed and clipped
}

// ---------------- weight abs-mean (deterministic two-stage fp64) ------------
__global__ __launch_bounds__(256) void absmean_part_k(
    const float* __restrict__ W, int n4, double* __restrict__ part)
{
  double s = 0.0;
  const int stride = gridDim.x * 256;
  for (int i = blockIdx.x * 256 + threadIdx.x; i < n4; i += stride) {
    float4 v = ((const float4*)W)[i];
    s += (double)fabsf(v.x); s += (double)fabsf(v.y);
    s += (double)fabsf(v.z); s += (double)fabsf(v.w);
  }
  __shared__ double sd[256];
  sd[threadIdx.x] = s;
  __syncthreads();
  for (int st = 128; st > 0; st >>= 1) {
    if (threadIdx.x < st) sd[threadIdx.x] += sd[threadIdx.x + st];
    __syncthreads();
  }
  if (threadIdx.x == 0) part[blockIdx.x] = sd[0];
}

__global__ __launch_bounds__(256) void absmean_fin_k(
    const double* __restrict__ part, int nPart, double n,
    float* __restrict__ wsc, int widx)
{
  __shared__ double sd[256];
  double s = 0.0;
  for (int i = threadIdx.x; i < nPart; i += 256) s += part[i];
  sd[threadIdx.x] = s;
  __syncthreads();
  for (int st = 128; st > 0; st >>= 1) {
    if (threadIdx.x < st) sd[threadIdx.x] += sd[threadIdx.x + st];
    __syncthreads();
  }
  if (threadIdx.x == 0) {
    float mean = (float)(sd[0] / n);
    float scale = 1.f / fmaxf(mean, 1e-5f);
    wsc[widx * 2]     = scale;
    wsc[widx * 2 + 1] = 1.f / scale;
  }
}

// ---------------- weight ternary quantization to i8 {-1,0,1} (w1, w4) -------
__global__ __launch_bounds__(256) void quant_w_k(
    const float* __restrict__ W, unsigned int* __restrict__ Wq,
    const float* __restrict__ wsc, int widx, int n4)
{
  const float s = wsc[widx * 2];
  const int stride = gridDim.x * 256;
  for (int i = blockIdx.x * 256 + threadIdx.x; i < n4; i += stride) {
    float4 v = ((const float4*)W)[i];
    unsigned int u =
        (unsigned int)f2i8(fminf(fmaxf(rintf(v.x * s), -1.f), 1.f)) |
        ((unsigned int)f2i8(fminf(fmaxf(rintf(v.y * s), -1.f), 1.f)) << 8) |
        ((unsigned int)f2i8(fminf(fmaxf(rintf(v.z * s), -1.f), 1.f)) << 16) |
        ((unsigned int)f2i8(fminf(fmaxf(rintf(v.w * s), -1.f), 1.f)) << 24);
    Wq[i] = u;
  }
}

// ---------------- weight ternary quantization to 2-bit packed (w2, w3) ------
// Wp[kc][o], kc = k/16; crumb for k = kc*16 + (m + 4*j) at byte m, bits 2j.
__global__ __launch_bounds__(256) void quant_w_pack_k(
    const float* __restrict__ W, unsigned int* __restrict__ Wp,
    const float* __restrict__ wsc, int widx, int Kd, int Nd)
{
  const float s = wsc[widx * 2];
  const int idx = blockIdx.x * 256 + threadIdx.x;
  const int kc = idx & (Kd / 16 - 1);
  const int o  = idx / (Kd / 16);
  if (o >= Nd) return;
  const float* wr = W + (size_t)o * Kd + kc * 16;
  unsigned int u = 0;
  #pragma unroll
  for (int e = 0; e < 16; ++e) {
    int q = (int)fminf(fmaxf(rintf(wr[e] * s), -1.f), 1.f);
    u |= (unsigned int)(q & 3) << (8 * (e & 3) + 2 * (e >> 2));
  }
  Wp[(size_t)kc * Nd + o] = u;
}

// ---------------- per-row activation quantization to i8 ---------------------
template<int D>
__global__ __launch_bounds__(256) void act_quant_k(
    const float* __restrict__ X, unsigned int* __restrict__ Xq,
    float* __restrict__ inv_sa)
{
  constexpr int PER = D / 1024;
  const int row = blockIdx.x, tid = threadIdx.x;
  const float4* xr = (const float4*)(X + (size_t)row * D);
  float4 v[PER];
  float m = 0.f;
  #pragma unroll
  for (int i = 0; i < PER; ++i) {
    v[i] = xr[tid + 256 * i];
    m = fmaxf(m, fmaxf(fmaxf(fabsf(v[i].x), fabsf(v[i].y)),
                       fmaxf(fabsf(v[i].z), fabsf(v[i].w))));
  }
  #pragma unroll
  for (int off = 32; off >= 1; off >>= 1) m = fmaxf(m, __shfl_xor(m, off));
  __shared__ float wm[4];
  if ((tid & 63) == 0) wm[tid >> 6] = m;
  __syncthreads();
  m = fmaxf(fmaxf(wm[0], wm[1]), fmaxf(wm[2], wm[3]));
  const float s = 127.f / fmaxf(m, 1e-5f);
  if (tid == 0) inv_sa[row] = 1.f / s;
  unsigned int* oq = Xq + (size_t)row * (D / 4);
  #pragma unroll
  for (int i = 0; i < PER; ++i) {
    unsigned int u =
        (unsigned int)f2i8(fminf(fmaxf(rintf(v[i].x * s), -128.f), 127.f)) |
        ((unsigned int)f2i8(fminf(fmaxf(rintf(v[i].y * s), -128.f), 127.f)) << 8) |
        ((unsigned int)f2i8(fminf(fmaxf(rintf(v[i].z * s), -128.f), 127.f)) << 16) |
        ((unsigned int)f2i8(fminf(fmaxf(rintf(v[i].w * s), -128.f), 127.f)) << 24);
    oq[tid + 256 * i] = u;
  }
}

// ---------------- 128^2 2-phase i8 GEMM (proven; used for L1/L4) ------------
template<int K, int N, bool TANH>
__global__ __launch_bounds__(256) void gemm_bt(
    const signed char* __restrict__ A, const signed char* __restrict__ W,
    const float* __restrict__ inv_sa, const float* __restrict__ wsc, int widx,
    const float* __restrict__ bias, float* __restrict__ out)
{
  __shared__ __align__(16) signed char As[128 * 64];
  __shared__ __align__(16) signed char Bs[128 * 64];
  const int tid = threadIdx.x;
  const int wv = tid >> 6, ln = tid & 63;
  const int bm = blockIdx.y, bn = blockIdx.x;
  const int wr = wv >> 1, wc = wv & 1;
  const signed char* Ab = A + (size_t)bm * 128 * K;
  const signed char* Wb = W + (size_t)bn * 128 * K;
  i32x4_t acc[4][4];
  #pragma unroll
  for (int m = 0; m < 4; ++m)
    #pragma unroll
    for (int n = 0; n < 4; ++n) acc[m][n] = (i32x4_t){0, 0, 0, 0};

  for (int k0 = 0; k0 < K; k0 += 64) {
    #pragma unroll
    for (int l = 0; l < 2; ++l) {
      const int c = l * 256 + wv * 64 + ln;
      const int row = c >> 2;
      const int kc = (c & 3) * 16;
      GLDS16(Ab + (size_t)row * K + k0 + kc, As + (l * 256 + wv * 64) * 16);
      GLDS16(Wb + (size_t)row * K + k0 + kc, Bs + (l * 256 + wv * 64) * 16);
    }
    __syncthreads();
    i32x4_t aw[4], bw[4];
    #pragma unroll
    for (int m = 0; m < 4; ++m)
      aw[m] = *(const i32x4_t*)(As + (wr * 64 + m * 16 + (ln & 15)) * 64 + (ln >> 4) * 16);
    #pragma unroll
    for (int n = 0; n < 4; ++n)
      bw[n] = *(const i32x4_t*)(Bs + (wc * 64 + n * 16 + (ln & 15)) * 64 + (ln >> 4) * 16);
    #pragma unroll
    for (int m = 0; m < 4; ++m)
      #pragma unroll
      for (int n = 0; n < 4; ++n)
        acc[m][n] = __builtin_amdgcn_mfma_i32_16x16x64_i8(aw[m], bw[n], acc[m][n], 0, 0, 0);
    __syncthreads();
  }

  const float invw = wsc[widx * 2 + 1];
  #pragma unroll
  for (int m = 0; m < 4; ++m) {
    const int gb0 = bm * 128 + wr * 64 + m * 16 + ((ln >> 4) << 2);
    #pragma unroll
    for (int r = 0; r < 4; ++r) {
      const int gb = gb0 + r;
      const float fa = inv_sa[gb] * invw;
      #pragma unroll
      for (int n = 0; n < 4; ++n) {
        const int go = bn * 128 + wc * 64 + n * 16 + (ln & 15);
        const float v = (float)acc[m][n][r] * fa + bias[go];
        out[(size_t)gb * N + go] = TANH ? tanhf(v) : v;
      }
    }
  }
}

// ---------------- 256x128 dbuf i8-A / 2-bit-B GEMM, 2 blocks/CU (L2/L3) -----
// BM=256, BN=128, BK=128. 8 waves (4M x 2N), per-wave output 64x64 ->
// acc = 4x4 frags = 64 AGPR. LDS/buf: A 32KB (3-bit XOR swizzle, r7-verified
// conflict-free) + B 4KB packed (8 x 512B kc-slices, parity-XOR banking).
// dbuf = 73728 B -> 2 blocks/CU at launch_bounds(512,4) (128 unified regs).
// B staged by waves 0-3 only (1 GLDS); all waves stage 4 A-GLDS.
// vmcnt(4) guarantees tile t+1 resident for all waves.
template<int K, int N, bool TANH>
__global__ __launch_bounds__(512, 4) void gemm2p(
    const signed char* __restrict__ A, const unsigned int* __restrict__ Wp,
    const float* __restrict__ inv_sa, const float* __restrict__ wsc, int widx,
    const float* __restrict__ bias, float* __restrict__ out)
{
  constexpr int BUFSZ = 32768 + 4096;               // 36864 B per buffer
  __shared__ __align__(16) signed char lds[2 * BUFSZ];
  constexpr int NT = K / 128;
  const int tid = threadIdx.x;
  const int wv = tid >> 6, ln = tid & 63;
  const int wr = wv >> 1, wc = wv & 1;              // 4 x 2 wave grid
  const int g = ln >> 4, rl = ln & 15;
  const int colswz = (rl & 7) << 4;                 // A read-side 3-bit XOR

  // XCD-aware block swizzle (nwg % 8 == 0)
  const int nwg = gridDim.x * gridDim.y;
  int lbid = blockIdx.y * gridDim.x + blockIdx.x;
  lbid = (lbid & 7) * (nwg >> 3) + (lbid >> 3);
  const int bn = lbid % gridDim.x, bm = lbid / gridDim.x;

  const signed char* Abase = A + (size_t)bm * 256 * K;
  const unsigned int* Wpb = Wp + (size_t)bn * 128;  // [kc][N] cols bn*128..

  // A: LDS chunk c (linear dest) <- global chunk c ^ ((c>>3)&7)  (2048 chunks)
  // B: thread tid<256: kc=tid>>5, j=tid&31; dest kc*512 + j*16; source dword
  //    base (4j) ^ ((kc&1)<<4)  (parity XOR both sides).
  auto stage = [&](int tt) {
    if (tt >= NT) return;
    signed char* dA = lds + (tt & 1) * BUFSZ;
    #pragma unroll
    for (int i = 0; i < 4; ++i) {
      const int c = tid + 512 * i;
      GLDS16(Abase + (size_t)(c >> 3) * K + tt * 128 + ((c ^ (c >> 3)) & 7) * 16,
             dA + c * 16);
    }
    if (wv < 4) {
      const int kc = tid >> 5, j = tid & 31;
      GLDS16(Wpb + (size_t)(tt * 8 + kc) * N + ((4 * j) ^ ((kc & 1) << 4)),
             dA + 32768 + kc * 512 + j * 16);
    }
  };

  i32x4_t acc[4][4];
  #pragma unroll
  for (int m = 0; m < 4; ++m)
    #pragma unroll
    for (int n = 0; n < 4; ++n) acc[m][n] = (i32x4_t){0, 0, 0, 0};

  const int myAoff = wr * 8192;                     // wr*64 rows * 128B
  const int bcol = wc * 64;

  // prologue
  stage(0); stage(1);
  asm volatile("s_waitcnt vmcnt(4)" ::: "memory");
  __builtin_amdgcn_s_barrier();

  for (int t = 0; t < NT; ++t) {
    const signed char* base = lds + (t & 1) * BUFSZ;
    const signed char* mA = base + myAoff;
    const unsigned int* mB = (const unsigned int*)(base + 32768);

    // packed B dwords (8 regs)
    unsigned int bp[2][4];
    #pragma unroll
    for (int ks = 0; ks < 2; ++ks)
      #pragma unroll
      for (int n = 0; n < 4; ++n)
        bp[ks][n] = mB[(ks * 4 + g) * 128
                       + ((bcol + n * 16 + rl) ^ ((g & 1) << 4))];

    __builtin_amdgcn_s_setprio(1);
    #pragma unroll
    for (int ks = 0; ks < 2; ++ks) {
      i32x4_t bu[4];
      #pragma unroll
      for (int n = 0; n < 4; ++n)
        #pragma unroll
        for (int j = 0; j < 4; ++j) {
          unsigned int tj = (bp[ks][n] >> (2 * j)) & 0x03030303u;
          bu[n][j] = (int)(tj | ((tj & 0x02020202u) * 0x7Fu));
        }
      #pragma unroll
      for (int m = 0; m < 4; ++m) {
        const i32x4_t af = *(const i32x4_t*)(
            mA + (m * 16 + rl) * 128 + ((ks * 64 + g * 16) ^ colswz));
        #pragma unroll
        for (int n = 0; n < 4; ++n)
          acc[m][n] = __builtin_amdgcn_mfma_i32_16x16x64_i8(
              af, bu[n], acc[m][n], 0, 0, 0);
      }
    }
    __builtin_amdgcn_s_setprio(0);

    asm volatile("s_waitcnt lgkmcnt(0)" ::: "memory");
    __builtin_amdgcn_s_barrier();            // all waves done reading buf[cur]
    stage(t + 2);                            // refill buf[cur] with tile t+2
    if (t + 2 < NT) asm volatile("s_waitcnt vmcnt(4)" ::: "memory");
    else            asm volatile("s_waitcnt vmcnt(0)" ::: "memory");
    __builtin_amdgcn_s_barrier();            // tile t+1 confirmed resident
  }

  // -------- epilogue --------
  const float invw = wsc[widx * 2 + 1];
  const int row0 = bm * 256 + wr * 64;
  const int col0 = bn * 128 + wc * 64;
  #pragma unroll
  for (int m = 0; m < 4; ++m) {
    #pragma unroll
    for (int r = 0; r < 4; ++r) {
      const int gb = row0 + m * 16 + g * 4 + r;
      const float fa = inv_sa[gb] * invw;
      #pragma unroll
      for (int n = 0; n < 4; ++n) {
        const int go = col0 + n * 16 + rl;
        const float v = (float)acc[m][n][r] * fa + bias[go];
        out[(size_t)gb * N + go] = TANH ? tanhf(v) : v;
      }
    }
  }
}

// ---------------- driver ----------------------------------------------------
extern "C" void kernel_launch(void* const* d_in, const int* in_sizes, int n_in,
                              void* d_out, int out_size, void* d_ws, size_t ws_size,
                              hipStream_t stream)
{
  const float* x  = (const float*)d_in[0];
  const float* w1 = (const float*)d_in[1]; const float* b1 = (const float*)d_in[2];
  const float* w2 = (const float*)d_in[3]; const float* b2 = (const float*)d_in[4];
  const float* w3 = (const float*)d_in[5]; const float* b3 = (const float*)d_in[6];
  const float* w4 = (const float*)d_in[7]; const float* b4 = (const float*)d_in[8];
  float* out = (float*)d_out;

  constexpr int B = 8192, DIN = 1024, H = 4096, DOUT = 1024;
  char* ws = (char*)d_ws;
  size_t off = 0;
  float*        hbuf = (float*)(ws + off);        off += (size_t)B * H * 4;
  signed char*  xq   = (signed char*)(ws + off);  off += (size_t)B * H;
  signed char*  wq   = (signed char*)(ws + off);  off += (size_t)H * H;     // i8 (w1/w4)
  unsigned int* wp2  = (unsigned int*)(ws + off); off += (size_t)(H / 16) * H * 4;
  unsigned int* wp3  = (unsigned int*)(ws + off); off += (size_t)(H / 16) * H * 4;
  float*        inv_sa = (float*)(ws + off);      off += (size_t)B * 4;
  double*       part = (double*)(ws + off);       off += 1024 * 8;
  float*        wsc  = (float*)(ws + off);        off += 64;

  absmean_part_k<<<1024, 256, 0, stream>>>(w1, H * DIN / 4, part);
  absmean_fin_k<<<1, 256, 0, stream>>>(part, 1024, (double)H * DIN, wsc, 0);
  absmean_part_k<<<1024, 256, 0, stream>>>(w2, H * H / 4, part);
  absmean_fin_k<<<1, 256, 0, stream>>>(part, 1024, (double)H * H, wsc, 1);
  absmean_part_k<<<1024, 256, 0, stream>>>(w3, H * H / 4, part);
  absmean_fin_k<<<1, 256, 0, stream>>>(part, 1024, (double)H * H, wsc, 2);
  absmean_part_k<<<1024, 256, 0, stream>>>(w4, DOUT * H / 4, part);
  absmean_fin_k<<<1, 256, 0, stream>>>(part, 1024, (double)DOUT * H, wsc, 3);

  // layer 1 (K=1024): 128^2 i8 kernel
  act_quant_k<DIN><<<B, 256, 0, stream>>>(x, (unsigned int*)xq, inv_sa);
  quant_w_k<<<2048, 256, 0, stream>>>(w1, (unsigned int*)wq, wsc, 0, H * DIN / 4);
  gemm_bt<DIN, H, true><<<dim3(H / 128, B / 128), 256, 0, stream>>>(
      xq, wq, inv_sa, wsc, 0, b1, hbuf);

  // layer 2: 256x128 packed-B, 2 blocks/CU
  act_quant_k<H><<<B, 256, 0, stream>>>(hbuf, (unsigned int*)xq, inv_sa);
  quant_w_pack_k<<<(H / 16) * H / 256, 256, 0, stream>>>(w2, wp2, wsc, 1, H, H);
  gemm2p<H, H, true><<<dim3(H / 128, B / 256), 512, 0, stream>>>(
      xq, wp2, inv_sa, wsc, 1, b2, hbuf);

  // layer 3: 256x128 packed-B, 2 blocks/CU
  act_quant_k<H><<<B, 256, 0, stream>>>(hbuf, (unsigned int*)xq, inv_sa);
  quant_w_pack_k<<<(H / 16) * H / 256, 256, 0, stream>>>(w3, wp3, wsc, 2, H, H);
  gemm2p<H, H, true><<<dim3(H / 128, B / 256), 512, 0, stream>>>(
      xq, wp3, inv_sa, wsc, 2, b3, hbuf);

  // layer 4 (N=1024): 128^2 i8 kernel
  act_quant_k<H><<<B, 256, 0, stream>>>(hbuf, (unsigned int*)xq, inv_sa);
  quant_w_k<<<2048, 256, 0, stream>>>(w4, (unsigned int*)wq, wsc, 3, DOUT * H / 4);
  gemm_bt<H, DOUT, false><<<dim3(DOUT / 128, B / 128), 256, 0, stream>>>(
      xq, wq, inv_sa, wsc, 3, b4, out);
}

// Round 12
// 574.039 us; speedup vs baseline: 6.7358x; 1.0354x over previous
//
#include <hip/hip_runtime.h>
#include <hip/hip_bf16.h>

// BitNet 4-layer MLP forward, MI355X — round 12: r11 VALU diet with the
// B-address fold FIXED. r11 folded 64*(np^(g&1)) as 64*(g&1)+64*np (wrong for
// g,np both odd -> wrong column + slice overflow). Restored XOR, kept hoisted:
// be[np] = boffB + ((np*64) ^ ((g&1)<<6)), precomputed outside the K-loop.

typedef __attribute__((ext_vector_type(4))) int i32x4_t;

#define GLDS16(g, l) __builtin_amdgcn_global_load_lds( \
    (const __attribute__((address_space(1))) unsigned int*)(g), \
    (__attribute__((address_space(3))) unsigned int*)(l), 16, 0, 0)

static __device__ __forceinline__ unsigned char f2i8(float f) {
  return (unsigned char)(int)f;   // f already rint'ed and clipped
}

// ---------------- weight abs-mean (deterministic two-stage fp64) ------------
__global__ __launch_bounds__(256) void absmean_part_k(
    const float* __restrict__ W, int n4, double* __restrict__ part)
{
  double s = 0.0;
  const int stride = gridDim.x * 256;
  for (int i = blockIdx.x * 256 + threadIdx.x; i < n4; i += stride) {
    float4 v = ((const float4*)W)[i];
    s += (double)fabsf(v.x); s += (double)fabsf(v.y);
    s += (double)fabsf(v.z); s += (double)fabsf(v.w);
  }
  __shared__ double sd[256];
  sd[threadIdx.x] = s;
  __syncthreads();
  for (int st = 128; st > 0; st >>= 1) {
    if (threadIdx.x < st) sd[threadIdx.x] += sd[threadIdx.x + st];
    __syncthreads();
  }
  if (threadIdx.x == 0) part[blockIdx.x] = sd[0];
}

__global__ __launch_bounds__(256) void absmean_fin_k(
    const double* __restrict__ part, int nPart, double n,
    float* __restrict__ wsc, int widx)
{
  __shared__ double sd[256];
  double s = 0.0;
  for (int i = threadIdx.x; i < nPart; i += 256) s += part[i];
  sd[threadIdx.x] = s;
  __syncthreads();
  for (int st = 128; st > 0; st >>= 1) {
    if (threadIdx.x < st) sd[threadIdx.x] += sd[threadIdx.x + st];
    __syncthreads();
  }
  if (threadIdx.x == 0) {
    float mean = (float)(sd[0] / n);
    float scale = 1.f / fmaxf(mean, 1e-5f);
    wsc[widx * 2]     = scale;
    wsc[widx * 2 + 1] = 1.f / scale;
  }
}

// ---------------- weight ternary quantization to i8 {-1,0,1} (w1, w4) -------
__global__ __launch_bounds__(256) void quant_w_k(
    const float* __restrict__ W, unsigned int* __restrict__ Wq,
    const float* __restrict__ wsc, int widx, int n4)
{
  const float s = wsc[widx * 2];
  const int stride = gridDim.x * 256;
  for (int i = blockIdx.x * 256 + threadIdx.x; i < n4; i += stride) {
    float4 v = ((const float4*)W)[i];
    unsigned int u =
        (unsigned int)f2i8(fminf(fmaxf(rintf(v.x * s), -1.f), 1.f)) |
        ((unsigned int)f2i8(fminf(fmaxf(rintf(v.y * s), -1.f), 1.f)) << 8) |
        ((unsigned int)f2i8(fminf(fmaxf(rintf(v.z * s), -1.f), 1.f)) << 16) |
        ((unsigned int)f2i8(fminf(fmaxf(rintf(v.w * s), -1.f), 1.f)) << 24);
    Wq[i] = u;
  }
}

// ---------------- weight ternary quantization to 2-bit packed (w2, w3) ------
// Wp[kc][o], kc = k/16; crumb for k = kc*16 + (m + 4*j) at byte m, bits 2j.
__global__ __launch_bounds__(256) void quant_w_pack_k(
    const float* __restrict__ W, unsigned int* __restrict__ Wp,
    const float* __restrict__ wsc, int widx, int Kd, int Nd)
{
  const float s = wsc[widx * 2];
  const int idx = blockIdx.x * 256 + threadIdx.x;
  const int kc = idx & (Kd / 16 - 1);
  const int o  = idx / (Kd / 16);
  if (o >= Nd) return;
  const float* wr = W + (size_t)o * Kd + kc * 16;
  unsigned int u = 0;
  #pragma unroll
  for (int e = 0; e < 16; ++e) {
    int q = (int)fminf(fmaxf(rintf(wr[e] * s), -1.f), 1.f);
    u |= (unsigned int)(q & 3) << (8 * (e & 3) + 2 * (e >> 2));
  }
  Wp[(size_t)kc * Nd + o] = u;
}

// ---------------- per-row activation quantization to i8 ---------------------
template<int D>
__global__ __launch_bounds__(256) void act_quant_k(
    const float* __restrict__ X, unsigned int* __restrict__ Xq,
    float* __restrict__ inv_sa)
{
  constexpr int PER = D / 1024;
  const int row = blockIdx.x, tid = threadIdx.x;
  const float4* xr = (const float4*)(X + (size_t)row * D);
  float4 v[PER];
  float m = 0.f;
  #pragma unroll
  for (int i = 0; i < PER; ++i) {
    v[i] = xr[tid + 256 * i];
    m = fmaxf(m, fmaxf(fmaxf(fabsf(v[i].x), fabsf(v[i].y)),
                       fmaxf(fabsf(v[i].z), fabsf(v[i].w))));
  }
  #pragma unroll
  for (int off = 32; off >= 1; off >>= 1) m = fmaxf(m, __shfl_xor(m, off));
  __shared__ float wm[4];
  if ((tid & 63) == 0) wm[tid >> 6] = m;
  __syncthreads();
  m = fmaxf(fmaxf(wm[0], wm[1]), fmaxf(wm[2], wm[3]));
  const float s = 127.f / fmaxf(m, 1e-5f);
  if (tid == 0) inv_sa[row] = 1.f / s;
  unsigned int* oq = Xq + (size_t)row * (D / 4);
  #pragma unroll
  for (int i = 0; i < PER; ++i) {
    unsigned int u =
        (unsigned int)f2i8(fminf(fmaxf(rintf(v[i].x * s), -128.f), 127.f)) |
        ((unsigned int)f2i8(fminf(fmaxf(rintf(v[i].y * s), -128.f), 127.f)) << 8) |
        ((unsigned int)f2i8(fminf(fmaxf(rintf(v[i].z * s), -128.f), 127.f)) << 16) |
        ((unsigned int)f2i8(fminf(fmaxf(rintf(v[i].w * s), -128.f), 127.f)) << 24);
    oq[tid + 256 * i] = u;
  }
}

// ---------------- 128^2 2-phase i8 GEMM (proven; used for L1/L4) ------------
template<int K, int N, bool TANH>
__global__ __launch_bounds__(256) void gemm_bt(
    const signed char* __restrict__ A, const signed char* __restrict__ W,
    const float* __restrict__ inv_sa, const float* __restrict__ wsc, int widx,
    const float* __restrict__ bias, float* __restrict__ out)
{
  __shared__ __align__(16) signed char As[128 * 64];
  __shared__ __align__(16) signed char Bs[128 * 64];
  const int tid = threadIdx.x;
  const int wv = tid >> 6, ln = tid & 63;
  const int bm = blockIdx.y, bn = blockIdx.x;
  const int wr = wv >> 1, wc = wv & 1;
  const signed char* Ab = A + (size_t)bm * 128 * K;
  const signed char* Wb = W + (size_t)bn * 128 * K;
  i32x4_t acc[4][4];
  #pragma unroll
  for (int m = 0; m < 4; ++m)
    #pragma unroll
    for (int n = 0; n < 4; ++n) acc[m][n] = (i32x4_t){0, 0, 0, 0};

  for (int k0 = 0; k0 < K; k0 += 64) {
    #pragma unroll
    for (int l = 0; l < 2; ++l) {
      const int c = l * 256 + wv * 64 + ln;
      const int row = c >> 2;
      const int kc = (c & 3) * 16;
      GLDS16(Ab + (size_t)row * K + k0 + kc, As + (l * 256 + wv * 64) * 16);
      GLDS16(Wb + (size_t)row * K + k0 + kc, Bs + (l * 256 + wv * 64) * 16);
    }
    __syncthreads();
    i32x4_t aw[4], bw[4];
    #pragma unroll
    for (int m = 0; m < 4; ++m)
      aw[m] = *(const i32x4_t*)(As + (wr * 64 + m * 16 + (ln & 15)) * 64 + (ln >> 4) * 16);
    #pragma unroll
    for (int n = 0; n < 4; ++n)
      bw[n] = *(const i32x4_t*)(Bs + (wc * 64 + n * 16 + (ln & 15)) * 64 + (ln >> 4) * 16);
    #pragma unroll
    for (int m = 0; m < 4; ++m)
      #pragma unroll
      for (int n = 0; n < 4; ++n)
        acc[m][n] = __builtin_amdgcn_mfma_i32_16x16x64_i8(aw[m], bw[n], acc[m][n], 0, 0, 0);
    __syncthreads();
  }

  const float invw = wsc[widx * 2 + 1];
  #pragma unroll
  for (int m = 0; m < 4; ++m) {
    const int gb0 = bm * 128 + wr * 64 + m * 16 + ((ln >> 4) << 2);
    #pragma unroll
    for (int r = 0; r < 4; ++r) {
      const int gb = gb0 + r;
      const float fa = inv_sa[gb] * invw;
      #pragma unroll
      for (int n = 0; n < 4; ++n) {
        const int go = bn * 128 + wc * 64 + n * 16 + (ln & 15);
        const float v = (float)acc[m][n][r] * fa + bias[go];
        out[(size_t)gb * N + go] = TANH ? tanhf(v) : v;
      }
    }
  }
}

// ---------------- 256x128 dbuf i8-A / 2-bit-B GEMM, VALU-lean (L2/L3) -------
// Structure/swizzles/sync of r10 (passed, 0 conflicts, no spill), with:
// hoisted A read bases (reads = base + immediate), hoisted B offsets WITH the
// correct XOR slot permute, SWAR 2-bit sign-extend (no mul), hoisted staging.
template<int K, int N, bool TANH>
__global__ __launch_bounds__(512, 4) void gemm2p(
    const signed char* __restrict__ A, const unsigned int* __restrict__ Wp,
    const float* __restrict__ inv_sa, const float* __restrict__ wsc, int widx,
    const float* __restrict__ bias, float* __restrict__ out)
{
  constexpr int BUFSZ = 32768 + 4096;               // 36864 B per buffer
  __shared__ __align__(16) signed char lds[2 * BUFSZ];
  constexpr int NT = K / 128;
  const int tid = threadIdx.x;
  const int wv = tid >> 6, ln = tid & 63;
  const int wr = wv >> 1, wc = wv & 1;              // 4 x 2 wave grid
  const int g = ln >> 4, rl = ln & 15;
  const int colswz = (rl & 7) << 4;                 // A read-side 3-bit XOR

  // XCD-aware block swizzle (nwg % 8 == 0)
  const int nwg = gridDim.x * gridDim.y;
  int lbid = blockIdx.y * gridDim.x + blockIdx.x;
  lbid = (lbid & 7) * (nwg >> 3) + (lbid >> 3);
  const int bn = lbid % gridDim.x, bm = lbid / gridDim.x;

  const signed char* Abase = A + (size_t)bm * 256 * K;
  const signed char* Wpb = (const signed char*)(Wp + (size_t)bn * 128);

  // ---- hoisted per-lane constants ----
  const int myAoff = wr * 8192;
  const int bcol = wc * 64;
  // A read bases (byte offsets within a buffer)
  const int aoff0 = myAoff + rl * 128 + ((g * 16) ^ colswz);          // ks=0
  const int aoff1 = myAoff + rl * 128 + ((64 + g * 16) ^ colswz);     // ks=1
  // B read offsets: physical slot = np ^ (g&1)  (XOR, not add — r11 bug)
  const int bswz = (g & 1) << 6;
  const int boffB = 32768 + g * 512 + 4 * (bcol + rl);
  int be[4];
  #pragma unroll
  for (int np = 0; np < 4; ++np) be[np] = boffB + ((np * 64) ^ bswz);
  // stage offsets
  int srcA[4], dstA[4];
  #pragma unroll
  for (int i = 0; i < 4; ++i) {
    const int c = tid + 512 * i;
    srcA[i] = (c >> 3) * K + ((c ^ (c >> 3)) & 7) * 16;
    dstA[i] = c * 16;
  }
  const int kcs = tid >> 5, js = tid & 31;          // B-stage role (wv<4)
  const size_t srcB = (size_t)kcs * N * 4 + 4 * ((4 * js) ^ ((kcs & 1) << 4));
  const int dstB = 32768 + kcs * 512 + js * 16;

  auto stage = [&](int tt) {
    if (tt >= NT) return;
    signed char* dA = lds + (tt & 1) * BUFSZ;
    const signed char* sA = Abase + tt * 128;
    #pragma unroll
    for (int i = 0; i < 4; ++i) GLDS16(sA + srcA[i], dA + dstA[i]);
    if (wv < 4)
      GLDS16(Wpb + (size_t)tt * (N * 32) + srcB, dA + dstB);
  };

  i32x4_t acc[4][4];
  #pragma unroll
  for (int m = 0; m < 4; ++m)
    #pragma unroll
    for (int n = 0; n < 4; ++n) acc[m][n] = (i32x4_t){0, 0, 0, 0};

  // prologue
  stage(0); stage(1);
  asm volatile("s_waitcnt vmcnt(4)" ::: "memory");
  __builtin_amdgcn_s_barrier();

  for (int t = 0; t < NT; ++t) {
    const signed char* bufb = lds + (t & 1) * BUFSZ;
    const signed char* pa0 = bufb + aoff0;
    const signed char* pa1 = bufb + aoff1;

    unsigned int bp[2][4];
    #pragma unroll
    for (int ks = 0; ks < 2; ++ks)
      #pragma unroll
      for (int np = 0; np < 4; ++np)
        bp[ks][np] = *(const unsigned int*)(bufb + be[np] + ks * 2048);

    __builtin_amdgcn_s_setprio(1);
    #pragma unroll
    for (int ks = 0; ks < 2; ++ks) {
      i32x4_t bu[4];
      #pragma unroll
      for (int np = 0; np < 4; ++np)
        #pragma unroll
        for (int j = 0; j < 4; ++j) {
          unsigned int tj = (bp[ks][np] >> (2 * j)) & 0x03030303u;
          // SWAR 2-bit sign-extend: 0->0, 1->1, 3->0xFF (no mul, no borrow)
          bu[np][j] = (int)(((tj ^ 0x82828282u) - 0x02020202u) ^ 0x80808080u);
        }
      const signed char* pa = ks ? pa1 : pa0;
      #pragma unroll
      for (int m = 0; m < 4; ++m) {
        const i32x4_t af = *(const i32x4_t*)(pa + m * 2048);
        #pragma unroll
        for (int np = 0; np < 4; ++np)
          acc[m][np] = __builtin_amdgcn_mfma_i32_16x16x64_i8(
              af, bu[np], acc[m][np], 0, 0, 0);
      }
    }
    __builtin_amdgcn_s_setprio(0);

    asm volatile("s_waitcnt lgkmcnt(0)" ::: "memory");
    __builtin_amdgcn_s_barrier();            // all waves done reading buf[cur]
    stage(t + 2);                            // refill buf[cur] with tile t+2
    if (t + 2 < NT) asm volatile("s_waitcnt vmcnt(4)" ::: "memory");
    else            asm volatile("s_waitcnt vmcnt(0)" ::: "memory");
    __builtin_amdgcn_s_barrier();            // tile t+1 confirmed resident
  }

  // -------- epilogue --------
  const float invw = wsc[widx * 2 + 1];
  const int row0 = bm * 256 + wr * 64;
  const int col0 = bn * 128 + wc * 64;
  #pragma unroll
  for (int m = 0; m < 4; ++m) {
    #pragma unroll
    for (int r = 0; r < 4; ++r) {
      const int gb = row0 + m * 16 + g * 4 + r;
      const float fa = inv_sa[gb] * invw;
      #pragma unroll
      for (int np = 0; np < 4; ++np) {
        const int go = col0 + np * 16 + rl;
        const float v = (float)acc[m][np][r] * fa + bias[go];
        out[(size_t)gb * N + go] = TANH ? tanhf(v) : v;
      }
    }
  }
}

// ---------------- driver ----------------------------------------------------
extern "C" void kernel_launch(void* const* d_in, const int* in_sizes, int n_in,
                              void* d_out, int out_size, void* d_ws, size_t ws_size,
                              hipStream_t stream)
{
  const float* x  = (const float*)d_in[0];
  const float* w1 = (const float*)d_in[1]; const float* b1 = (const float*)d_in[2];
  const float* w2 = (const float*)d_in[3]; const float* b2 = (const float*)d_in[4];
  const float* w3 = (const float*)d_in[5]; const float* b3 = (const float*)d_in[6];
  const float* w4 = (const float*)d_in[7]; const float* b4 = (const float*)d_in[8];
  float* out = (float*)d_out;

  constexpr int B = 8192, DIN = 1024, H = 4096, DOUT = 1024;
  char* ws = (char*)d_ws;
  size_t off = 0;
  float*        hbuf = (float*)(ws + off);        off += (size_t)B * H * 4;
  signed char*  xq   = (signed char*)(ws + off);  off += (size_t)B * H;
  signed char*  wq   = (signed char*)(ws + off);  off += (size_t)H * H;     // i8 (w1/w4)
  unsigned int* wp2  = (unsigned int*)(ws + off); off += (size_t)(H / 16) * H * 4;
  unsigned int* wp3  = (unsigned int*)(ws + off); off += (size_t)(H / 16) * H * 4;
  float*        inv_sa = (float*)(ws + off);      off += (size_t)B * 4;
  double*       part = (double*)(ws + off);       off += 1024 * 8;
  float*        wsc  = (float*)(ws + off);        off += 64;

  absmean_part_k<<<1024, 256, 0, stream>>>(w1, H * DIN / 4, part);
  absmean_fin_k<<<1, 256, 0, stream>>>(part, 1024, (double)H * DIN, wsc, 0);
  absmean_part_k<<<1024, 256, 0, stream>>>(w2, H * H / 4, part);
  absmean_fin_k<<<1, 256, 0, stream>>>(part, 1024, (double)H * H, wsc, 1);
  absmean_part_k<<<1024, 256, 0, stream>>>(w3, H * H / 4, part);
  absmean_fin_k<<<1, 256, 0, stream>>>(part, 1024, (double)H * H, wsc, 2);
  absmean_part_k<<<1024, 256, 0, stream>>>(w4, DOUT * H / 4, part);
  absmean_fin_k<<<1, 256, 0, stream>>>(part, 1024, (double)DOUT * H, wsc, 3);

  // layer 1 (K=1024): 128^2 i8 kernel
  act_quant_k<DIN><<<B, 256, 0, stream>>>(x, (unsigned int*)xq, inv_sa);
  quant_w_k<<<2048, 256, 0, stream>>>(w1, (unsigned int*)wq, wsc, 0, H * DIN / 4);
  gemm_bt<DIN, H, true><<<dim3(H / 128, B / 128), 256, 0, stream>>>(
      xq, wq, inv_sa, wsc, 0, b1, hbuf);

  // layer 2: 256x128 packed-B, VALU-lean
  act_quant_k<H><<<B, 256, 0, stream>>>(hbuf, (unsigned int*)xq, inv_sa);
  quant_w_pack_k<<<(H / 16) * H / 256, 256, 0, stream>>>(w2, wp2, wsc, 1, H, H);
  gemm2p<H, H, true><<<dim3(H / 128, B / 256), 512, 0, stream>>>(
      xq, wp2, inv_sa, wsc, 1, b2, hbuf);

  // layer 3
  act_quant_k<H><<<B, 256, 0, stream>>>(hbuf, (unsigned int*)xq, inv_sa);
  quant_w_pack_k<<<(H / 16) * H / 256, 256, 0, stream>>>(w3, wp3, wsc, 2, H, H);
  gemm2p<H, H, true><<<dim3(H / 128, B / 256), 512, 0, stream>>>(
      xq, wp3, inv_sa, wsc, 2, b3, hbuf);

  // layer 4 (N=1024): 128^2 i8 kernel
  act_quant_k<H><<<B, 256, 0, stream>>>(hbuf, (unsigned int*)xq, inv_sa);
  quant_w_k<<<2048, 256, 0, stream>>>(w4, (unsigned int*)wq, wsc, 3, DOUT * H / 4);
  gemm_bt<H, DOUT, false><<<dim3(DOUT / 128, B / 128), 256, 0, stream>>>(
      xq, wq, inv_sa, wsc, 3, b4, out);
}

// Round 13
// 534.861 us; speedup vs baseline: 7.2292x; 1.0732x over previous
//
#include <hip/hip_runtime.h>
#include <hip/hip_bf16.h>

// BitNet 4-layer MLP forward, MI355X — round 13: biased-weight unpack + all
// layers on gemm2p. w' = w+1 in {0,1,2} stored in 2-bit crumbs -> unpack is
// shift+and only (8 VALU/dword vs 20); epilogue subtracts per-row activation
// sum S_r (integer-exact). L1/L4 ported to the 256x128 gemm2p template.

typedef __attribute__((ext_vector_type(4))) int i32x4_t;

#define GLDS16(g, l) __builtin_amdgcn_global_load_lds( \
    (const __attribute__((address_space(1))) unsigned int*)(g), \
    (__attribute__((address_space(3))) unsigned int*)(l), 16, 0, 0)

// ---------------- weight abs-mean (deterministic two-stage fp64) ------------
__global__ __launch_bounds__(256) void absmean_part_k(
    const float* __restrict__ W, int n4, double* __restrict__ part)
{
  double s = 0.0;
  const int stride = gridDim.x * 256;
  for (int i = blockIdx.x * 256 + threadIdx.x; i < n4; i += stride) {
    float4 v = ((const float4*)W)[i];
    s += (double)fabsf(v.x); s += (double)fabsf(v.y);
    s += (double)fabsf(v.z); s += (double)fabsf(v.w);
  }
  __shared__ double sd[256];
  sd[threadIdx.x] = s;
  __syncthreads();
  for (int st = 128; st > 0; st >>= 1) {
    if (threadIdx.x < st) sd[threadIdx.x] += sd[threadIdx.x + st];
    __syncthreads();
  }
  if (threadIdx.x == 0) part[blockIdx.x] = sd[0];
}

__global__ __launch_bounds__(256) void absmean_fin_k(
    const double* __restrict__ part, int nPart, double n,
    float* __restrict__ wsc, int widx)
{
  __shared__ double sd[256];
  double s = 0.0;
  for (int i = threadIdx.x; i < nPart; i += 256) s += part[i];
  sd[threadIdx.x] = s;
  __syncthreads();
  for (int st = 128; st > 0; st >>= 1) {
    if (threadIdx.x < st) sd[threadIdx.x] += sd[threadIdx.x + st];
    __syncthreads();
  }
  if (threadIdx.x == 0) {
    float mean = (float)(sd[0] / n);
    float scale = 1.f / fmaxf(mean, 1e-5f);
    wsc[widx * 2]     = scale;
    wsc[widx * 2 + 1] = 1.f / scale;
  }
}

// ------- weight ternary quantization to 2-bit packed, BIASED {0,1,2} --------
// Wp[kc][o], kc = k/16; crumb for k = kc*16 + (m + 4*j) at byte m, bits 2j.
// Stored value = w+1 in {0,1,2}; unpack dword j = (u >> 2j) & 0x03030303.
__global__ __launch_bounds__(256) void quant_w_pack_k(
    const float* __restrict__ W, unsigned int* __restrict__ Wp,
    const float* __restrict__ wsc, int widx, int Kd, int Nd)
{
  const float s = wsc[widx * 2];
  const int idx = blockIdx.x * 256 + threadIdx.x;
  const int kc = idx & (Kd / 16 - 1);
  const int o  = idx / (Kd / 16);
  if (o >= Nd) return;
  const float* wr = W + (size_t)o * Kd + kc * 16;
  unsigned int u = 0;
  #pragma unroll
  for (int e = 0; e < 16; ++e) {
    int q = (int)fminf(fmaxf(rintf(wr[e] * s), -1.f), 1.f);
    u |= (unsigned int)(q + 1) << (8 * (e & 3) + 2 * (e >> 2));
  }
  Wp[(size_t)kc * Nd + o] = u;
}

// ---------------- per-row activation quantization to i8 + row-sum -----------
template<int D>
__global__ __launch_bounds__(256) void act_quant_k(
    const float* __restrict__ X, unsigned int* __restrict__ Xq,
    float* __restrict__ inv_sa, int* __restrict__ rsum)
{
  constexpr int PER = D / 1024;
  const int row = blockIdx.x, tid = threadIdx.x;
  const float4* xr = (const float4*)(X + (size_t)row * D);
  float4 v[PER];
  float m = 0.f;
  #pragma unroll
  for (int i = 0; i < PER; ++i) {
    v[i] = xr[tid + 256 * i];
    m = fmaxf(m, fmaxf(fmaxf(fabsf(v[i].x), fabsf(v[i].y)),
                       fmaxf(fabsf(v[i].z), fabsf(v[i].w))));
  }
  #pragma unroll
  for (int off = 32; off >= 1; off >>= 1) m = fmaxf(m, __shfl_xor(m, off));
  __shared__ float wm[4];
  if ((tid & 63) == 0) wm[tid >> 6] = m;
  __syncthreads();
  m = fmaxf(fmaxf(wm[0], wm[1]), fmaxf(wm[2], wm[3]));
  const float s = 127.f / fmaxf(m, 1e-5f);
  if (tid == 0) inv_sa[row] = 1.f / s;
  unsigned int* oq = Xq + (size_t)row * (D / 4);
  int isum = 0;
  #pragma unroll
  for (int i = 0; i < PER; ++i) {
    const int qx = (int)fminf(fmaxf(rintf(v[i].x * s), -128.f), 127.f);
    const int qy = (int)fminf(fmaxf(rintf(v[i].y * s), -128.f), 127.f);
    const int qz = (int)fminf(fmaxf(rintf(v[i].z * s), -128.f), 127.f);
    const int qw = (int)fminf(fmaxf(rintf(v[i].w * s), -128.f), 127.f);
    isum += qx + qy + qz + qw;
    oq[tid + 256 * i] = (unsigned int)(qx & 255) | ((unsigned int)(qy & 255) << 8)
                      | ((unsigned int)(qz & 255) << 16) | ((unsigned int)(qw & 255) << 24);
  }
  #pragma unroll
  for (int off = 32; off >= 1; off >>= 1) isum += __shfl_xor(isum, off);
  __shared__ int wsum[4];
  if ((tid & 63) == 0) wsum[tid >> 6] = isum;
  __syncthreads();
  if (tid == 0) rsum[row] = wsum[0] + wsum[1] + wsum[2] + wsum[3];
}

// ------ 256x128 dbuf i8-A / 2-bit-biased-B GEMM, 2 blocks/CU (all layers) ---
// 8 waves (4M x 2N), per-wave 64x64, acc 64 AGPR. LDS/buf 36864 B.
// A: 3-bit XOR swizzle (conflict-free, r7-verified). B: 8 x 512B kc slices,
// parity-XOR slot permute. Unpack = shift+and (values {0,1,2}); epilogue
// subtracts rsum[row] (Sum_k q_x) to undo the +1 weight bias. Integer-exact.
template<int K, int N, bool TANH>
__global__ __launch_bounds__(512, 4) void gemm2p(
    const signed char* __restrict__ A, const unsigned int* __restrict__ Wp,
    const float* __restrict__ inv_sa, const int* __restrict__ rsum,
    const float* __restrict__ wsc, int widx,
    const float* __restrict__ bias, float* __restrict__ out)
{
  constexpr int BUFSZ = 32768 + 4096;               // 36864 B per buffer
  __shared__ __align__(16) signed char lds[2 * BUFSZ];
  constexpr int NT = K / 128;
  const int tid = threadIdx.x;
  const int wv = tid >> 6, ln = tid & 63;
  const int wr = wv >> 1, wc = wv & 1;              // 4 x 2 wave grid
  const int g = ln >> 4, rl = ln & 15;
  const int colswz = (rl & 7) << 4;                 // A read-side 3-bit XOR

  // XCD-aware block swizzle (nwg % 8 == 0 for all grids used)
  const int nwg = gridDim.x * gridDim.y;
  int lbid = blockIdx.y * gridDim.x + blockIdx.x;
  lbid = (lbid & 7) * (nwg >> 3) + (lbid >> 3);
  const int bn = lbid % gridDim.x, bm = lbid / gridDim.x;

  const signed char* Abase = A + (size_t)bm * 256 * K;
  const signed char* Wpb = (const signed char*)(Wp + (size_t)bn * 128);

  // ---- hoisted per-lane constants ----
  const int myAoff = wr * 8192;
  const int bcol = wc * 64;
  const int aoff0 = myAoff + rl * 128 + ((g * 16) ^ colswz);          // ks=0
  const int aoff1 = myAoff + rl * 128 + ((64 + g * 16) ^ colswz);     // ks=1
  const int bswz = (g & 1) << 6;
  const int boffB = 32768 + g * 512 + 4 * (bcol + rl);
  int be[4];
  #pragma unroll
  for (int np = 0; np < 4; ++np) be[np] = boffB + ((np * 64) ^ bswz);
  int srcA[4], dstA[4];
  #pragma unroll
  for (int i = 0; i < 4; ++i) {
    const int c = tid + 512 * i;
    srcA[i] = (c >> 3) * K + ((c ^ (c >> 3)) & 7) * 16;
    dstA[i] = c * 16;
  }
  const int kcs = tid >> 5, js = tid & 31;          // B-stage role (wv<4)
  const size_t srcB = (size_t)kcs * N * 4 + 4 * ((4 * js) ^ ((kcs & 1) << 4));
  const int dstB = 32768 + kcs * 512 + js * 16;

  auto stage = [&](int tt) {
    if (tt >= NT) return;
    signed char* dA = lds + (tt & 1) * BUFSZ;
    const signed char* sA = Abase + tt * 128;
    #pragma unroll
    for (int i = 0; i < 4; ++i) GLDS16(sA + srcA[i], dA + dstA[i]);
    if (wv < 4)
      GLDS16(Wpb + (size_t)tt * (N * 32) + srcB, dA + dstB);
  };

  i32x4_t acc[4][4];
  #pragma unroll
  for (int m = 0; m < 4; ++m)
    #pragma unroll
    for (int n = 0; n < 4; ++n) acc[m][n] = (i32x4_t){0, 0, 0, 0};

  // prologue
  stage(0); stage(1);
  asm volatile("s_waitcnt vmcnt(4)" ::: "memory");
  __builtin_amdgcn_s_barrier();

  for (int t = 0; t < NT; ++t) {
    const signed char* bufb = lds + (t & 1) * BUFSZ;
    const signed char* pa0 = bufb + aoff0;
    const signed char* pa1 = bufb + aoff1;

    unsigned int bp[2][4];
    #pragma unroll
    for (int ks = 0; ks < 2; ++ks)
      #pragma unroll
      for (int np = 0; np < 4; ++np)
        bp[ks][np] = *(const unsigned int*)(bufb + be[np] + ks * 2048);

    __builtin_amdgcn_s_setprio(1);
    #pragma unroll
    for (int ks = 0; ks < 2; ++ks) {
      i32x4_t bu[4];
      #pragma unroll
      for (int np = 0; np < 4; ++np)
        #pragma unroll
        for (int j = 0; j < 4; ++j)
          bu[np][j] = (int)((bp[ks][np] >> (2 * j)) & 0x03030303u);
      const signed char* pa = ks ? pa1 : pa0;
      #pragma unroll
      for (int m = 0; m < 4; ++m) {
        const i32x4_t af = *(const i32x4_t*)(pa + m * 2048);
        #pragma unroll
        for (int np = 0; np < 4; ++np)
          acc[m][np] = __builtin_amdgcn_mfma_i32_16x16x64_i8(
              af, bu[np], acc[m][np], 0, 0, 0);
      }
    }
    __builtin_amdgcn_s_setprio(0);

    asm volatile("s_waitcnt lgkmcnt(0)" ::: "memory");
    __builtin_amdgcn_s_barrier();            // all waves done reading buf[cur]
    stage(t + 2);                            // refill buf[cur] with tile t+2
    if (t + 2 < NT) asm volatile("s_waitcnt vmcnt(4)" ::: "memory");
    else            asm volatile("s_waitcnt vmcnt(0)" ::: "memory");
    __builtin_amdgcn_s_barrier();            // tile t+1 confirmed resident
  }

  // -------- epilogue: undo weight bias (acc - rowsum), scale, bias, tanh ----
  const float invw = wsc[widx * 2 + 1];
  const int row0 = bm * 256 + wr * 64;
  const int col0 = bn * 128 + wc * 64;
  #pragma unroll
  for (int m = 0; m < 4; ++m) {
    #pragma unroll
    for (int r = 0; r < 4; ++r) {
      const int gb = row0 + m * 16 + g * 4 + r;
      const float fa = inv_sa[gb] * invw;
      const int sr = rsum[gb];
      #pragma unroll
      for (int np = 0; np < 4; ++np) {
        const int go = col0 + np * 16 + rl;
        const float v = (float)(acc[m][np][r] - sr) * fa + bias[go];
        out[(size_t)gb * N + go] = TANH ? tanhf(v) : v;
      }
    }
  }
}

// ---------------- driver ----------------------------------------------------
extern "C" void kernel_launch(void* const* d_in, const int* in_sizes, int n_in,
                              void* d_out, int out_size, void* d_ws, size_t ws_size,
                              hipStream_t stream)
{
  const float* x  = (const float*)d_in[0];
  const float* w1 = (const float*)d_in[1]; const float* b1 = (const float*)d_in[2];
  const float* w2 = (const float*)d_in[3]; const float* b2 = (const float*)d_in[4];
  const float* w3 = (const float*)d_in[5]; const float* b3 = (const float*)d_in[6];
  const float* w4 = (const float*)d_in[7]; const float* b4 = (const float*)d_in[8];
  float* out = (float*)d_out;

  constexpr int B = 8192, DIN = 1024, H = 4096, DOUT = 1024;
  char* ws = (char*)d_ws;
  size_t off = 0;
  float*        hbuf = (float*)(ws + off);        off += (size_t)B * H * 4;
  signed char*  xq   = (signed char*)(ws + off);  off += (size_t)B * H;
  unsigned int* wp1  = (unsigned int*)(ws + off); off += (size_t)(DIN / 16) * H * 4;
  unsigned int* wp2  = (unsigned int*)(ws + off); off += (size_t)(H / 16) * H * 4;
  unsigned int* wp3  = (unsigned int*)(ws + off); off += (size_t)(H / 16) * H * 4;
  unsigned int* wp4  = (unsigned int*)(ws + off); off += (size_t)(H / 16) * DOUT * 4;
  float*        inv_sa = (float*)(ws + off);      off += (size_t)B * 4;
  int*          rsum = (int*)(ws + off);          off += (size_t)B * 4;
  double*       part = (double*)(ws + off);       off += 1024 * 8;
  float*        wsc  = (float*)(ws + off);        off += 64;

  absmean_part_k<<<1024, 256, 0, stream>>>(w1, H * DIN / 4, part);
  absmean_fin_k<<<1, 256, 0, stream>>>(part, 1024, (double)H * DIN, wsc, 0);
  absmean_part_k<<<1024, 256, 0, stream>>>(w2, H * H / 4, part);
  absmean_fin_k<<<1, 256, 0, stream>>>(part, 1024, (double)H * H, wsc, 1);
  absmean_part_k<<<1024, 256, 0, stream>>>(w3, H * H / 4, part);
  absmean_fin_k<<<1, 256, 0, stream>>>(part, 1024, (double)H * H, wsc, 2);
  absmean_part_k<<<1024, 256, 0, stream>>>(w4, DOUT * H / 4, part);
  absmean_fin_k<<<1, 256, 0, stream>>>(part, 1024, (double)DOUT * H, wsc, 3);

  // layer 1: K=DIN=1024, N=H
  act_quant_k<DIN><<<B, 256, 0, stream>>>(x, (unsigned int*)xq, inv_sa, rsum);
  quant_w_pack_k<<<H * (DIN / 16) / 256, 256, 0, stream>>>(w1, wp1, wsc, 0, DIN, H);
  gemm2p<DIN, H, true><<<dim3(H / 128, B / 256), 512, 0, stream>>>(
      xq, wp1, inv_sa, rsum, wsc, 0, b1, hbuf);

  // layer 2: K=H, N=H
  act_quant_k<H><<<B, 256, 0, stream>>>(hbuf, (unsigned int*)xq, inv_sa, rsum);
  quant_w_pack_k<<<H * (H / 16) / 256, 256, 0, stream>>>(w2, wp2, wsc, 1, H, H);
  gemm2p<H, H, true><<<dim3(H / 128, B / 256), 512, 0, stream>>>(
      xq, wp2, inv_sa, rsum, wsc, 1, b2, hbuf);

  // layer 3: K=H, N=H
  act_quant_k<H><<<B, 256, 0, stream>>>(hbuf, (unsigned int*)xq, inv_sa, rsum);
  quant_w_pack_k<<<H * (H / 16) / 256, 256, 0, stream>>>(w3, wp3, wsc, 2, H, H);
  gemm2p<H, H, true><<<dim3(H / 128, B / 256), 512, 0, stream>>>(
      xq, wp3, inv_sa, rsum, wsc, 2, b3, hbuf);

  // layer 4: K=H, N=DOUT, no tanh
  act_quant_k<H><<<B, 256, 0, stream>>>(hbuf, (unsigned int*)xq, inv_sa, rsum);
  quant_w_pack_k<<<DOUT * (H / 16) / 256, 256, 0, stream>>>(w4, wp4, wsc, 3, H, DOUT);
  gemm2p<H, DOUT, false><<<dim3(DOUT / 128, B / 256), 512, 0, stream>>>(
      xq, wp4, inv_sa, rsum, wsc, 3, b4, out);
}

// Round 14
// 481.926 us; speedup vs baseline: 8.0233x; 1.1098x over previous
//
#include <hip/hip_runtime.h>
#include <hip/hip_bf16.h>

// BitNet 4-layer MLP forward, MI355X — round 14: non-GEMM cleanup.
// gemm2p hot loop untouched (r13: 150us, VALU 44 / MFMA 39). Changes:
// fast tanh epilogue (1-2*rcp(e^2x+1), ~5 instr), merged absmean (8->2
// launches), merged float4-vectorized weight-pack (4->1 launches).

typedef __attribute__((ext_vector_type(4))) int i32x4_t;

#define GLDS16(g, l) __builtin_amdgcn_global_load_lds( \
    (const __attribute__((address_space(1))) unsigned int*)(g), \
    (__attribute__((address_space(3))) unsigned int*)(l), 16, 0, 0)

// ---------------- merged weight abs-mean: one pass over all 4 tensors -------
// blocks [0,128) w1 | [128,640) w2 | [640,1152) w3 | [1152,1280) w4
__global__ __launch_bounds__(256) void absmean4_part_k(
    const float* __restrict__ w1, const float* __restrict__ w2,
    const float* __restrict__ w3, const float* __restrict__ w4,
    double* __restrict__ part)
{
  const int b = blockIdx.x;
  const float* W; int n4, b0, nb;
  if (b < 128)       { W = w1; n4 = 1 << 20; b0 = 0;    nb = 128; }
  else if (b < 640)  { W = w2; n4 = 1 << 22; b0 = 128;  nb = 512; }
  else if (b < 1152) { W = w3; n4 = 1 << 22; b0 = 640;  nb = 512; }
  else               { W = w4; n4 = 1 << 20; b0 = 1152; nb = 128; }
  double s = 0.0;
  const int stride = nb * 256;
  for (int i = (b - b0) * 256 + threadIdx.x; i < n4; i += stride) {
    float4 v = ((const float4*)W)[i];
    s += (double)fabsf(v.x); s += (double)fabsf(v.y);
    s += (double)fabsf(v.z); s += (double)fabsf(v.w);
  }
  __shared__ double sd[256];
  sd[threadIdx.x] = s;
  __syncthreads();
  for (int st = 128; st > 0; st >>= 1) {
    if (threadIdx.x < st) sd[threadIdx.x] += sd[threadIdx.x + st];
    __syncthreads();
  }
  if (threadIdx.x == 0) part[b] = sd[0];
}

__global__ __launch_bounds__(256) void absmean4_fin_k(
    const double* __restrict__ part, float* __restrict__ wsc)
{
  __shared__ double sd[256];
  const int tid = threadIdx.x;
  const int seg[5] = {0, 128, 640, 1152, 1280};
  const double nel[4] = {4194304.0, 16777216.0, 16777216.0, 4194304.0};
  for (int si = 0; si < 4; ++si) {
    double s = 0.0;
    for (int i = seg[si] + tid; i < seg[si + 1]; i += 256) s += part[i];
    sd[tid] = s;
    __syncthreads();
    for (int st = 128; st > 0; st >>= 1) {
      if (tid < st) sd[tid] += sd[tid + st];
      __syncthreads();
    }
    if (tid == 0) {
      float mean = (float)(sd[0] / nel[si]);
      float scale = 1.f / fmaxf(mean, 1e-5f);
      wsc[si * 2]     = scale;
      wsc[si * 2 + 1] = 1.f / scale;
    }
    __syncthreads();
  }
}

// ------- merged weight pack (biased {0,1,2} 2-bit), float4-vectorized -------
// Wp[kc][o]; crumb for k = kc*16 + (c + 4*q4) at byte c, bits 2*q4.
// idx ranges: [0,256K) w1 | [256K,1.25M) w2 | [1.25M,2.25M) w3 | [2.25M,2.5M) w4
__global__ __launch_bounds__(256) void quant_w_pack4_k(
    const float* __restrict__ w1, const float* __restrict__ w2,
    const float* __restrict__ w3, const float* __restrict__ w4,
    unsigned int* __restrict__ wp1, unsigned int* __restrict__ wp2,
    unsigned int* __restrict__ wp3, unsigned int* __restrict__ wp4,
    const float* __restrict__ wsc)
{
  int idx = blockIdx.x * 256 + threadIdx.x;
  const float* W; unsigned int* Wp; int Kd, Nd, widx;
  if (idx < 262144)        { W = w1; Wp = wp1; Kd = 1024; Nd = 4096; widx = 0; }
  else if (idx < 1310720)  { idx -= 262144;  W = w2; Wp = wp2; Kd = 4096; Nd = 4096; widx = 1; }
  else if (idx < 2359296)  { idx -= 1310720; W = w3; Wp = wp3; Kd = 4096; Nd = 4096; widx = 2; }
  else                     { idx -= 2359296; W = w4; Wp = wp4; Kd = 4096; Nd = 1024; widx = 3; }
  const float s = wsc[widx * 2];
  const int kc = idx & (Kd / 16 - 1);
  const int o  = idx / (Kd / 16);
  const float4* wr = (const float4*)(W + (size_t)o * Kd + kc * 16);
  unsigned int u = 0;
  #pragma unroll
  for (int q4 = 0; q4 < 4; ++q4) {
    const float4 v = wr[q4];
    int q;
    q = (int)fminf(fmaxf(rintf(v.x * s), -1.f), 1.f); u |= (unsigned int)(q + 1) << (2 * q4);
    q = (int)fminf(fmaxf(rintf(v.y * s), -1.f), 1.f); u |= (unsigned int)(q + 1) << (8 + 2 * q4);
    q = (int)fminf(fmaxf(rintf(v.z * s), -1.f), 1.f); u |= (unsigned int)(q + 1) << (16 + 2 * q4);
    q = (int)fminf(fmaxf(rintf(v.w * s), -1.f), 1.f); u |= (unsigned int)(q + 1) << (24 + 2 * q4);
  }
  Wp[(size_t)kc * Nd + o] = u;
}

// ---------------- per-row activation quantization to i8 + row-sum -----------
template<int D>
__global__ __launch_bounds__(256) void act_quant_k(
    const float* __restrict__ X, unsigned int* __restrict__ Xq,
    float* __restrict__ inv_sa, int* __restrict__ rsum)
{
  constexpr int PER = D / 1024;
  const int row = blockIdx.x, tid = threadIdx.x;
  const float4* xr = (const float4*)(X + (size_t)row * D);
  float4 v[PER];
  float m = 0.f;
  #pragma unroll
  for (int i = 0; i < PER; ++i) {
    v[i] = xr[tid + 256 * i];
    m = fmaxf(m, fmaxf(fmaxf(fabsf(v[i].x), fabsf(v[i].y)),
                       fmaxf(fabsf(v[i].z), fabsf(v[i].w))));
  }
  #pragma unroll
  for (int off = 32; off >= 1; off >>= 1) m = fmaxf(m, __shfl_xor(m, off));
  __shared__ float wm[4];
  if ((tid & 63) == 0) wm[tid >> 6] = m;
  __syncthreads();
  m = fmaxf(fmaxf(wm[0], wm[1]), fmaxf(wm[2], wm[3]));
  const float s = 127.f / fmaxf(m, 1e-5f);
  if (tid == 0) inv_sa[row] = 1.f / s;
  unsigned int* oq = Xq + (size_t)row * (D / 4);
  int isum = 0;
  #pragma unroll
  for (int i = 0; i < PER; ++i) {
    const int qx = (int)fminf(fmaxf(rintf(v[i].x * s), -128.f), 127.f);
    const int qy = (int)fminf(fmaxf(rintf(v[i].y * s), -128.f), 127.f);
    const int qz = (int)fminf(fmaxf(rintf(v[i].z * s), -128.f), 127.f);
    const int qw = (int)fminf(fmaxf(rintf(v[i].w * s), -128.f), 127.f);
    isum += qx + qy + qz + qw;
    oq[tid + 256 * i] = (unsigned int)(qx & 255) | ((unsigned int)(qy & 255) << 8)
                      | ((unsigned int)(qz & 255) << 16) | ((unsigned int)(qw & 255) << 24);
  }
  #pragma unroll
  for (int off = 32; off >= 1; off >>= 1) isum += __shfl_xor(isum, off);
  __shared__ int wsum[4];
  if ((tid & 63) == 0) wsum[tid >> 6] = isum;
  __syncthreads();
  if (tid == 0) rsum[row] = wsum[0] + wsum[1] + wsum[2] + wsum[3];
}

// ------ 256x128 dbuf i8-A / 2-bit-biased-B GEMM, 2 blocks/CU (all layers) ---
// Identical to r13 (passed; 0 conflicts; no spill) except fast-tanh epilogue.
template<int K, int N, bool TANH>
__global__ __launch_bounds__(512, 4) void gemm2p(
    const signed char* __restrict__ A, const unsigned int* __restrict__ Wp,
    const float* __restrict__ inv_sa, const int* __restrict__ rsum,
    const float* __restrict__ wsc, int widx,
    const float* __restrict__ bias, float* __restrict__ out)
{
  constexpr int BUFSZ = 32768 + 4096;               // 36864 B per buffer
  __shared__ __align__(16) signed char lds[2 * BUFSZ];
  constexpr int NT = K / 128;
  const int tid = threadIdx.x;
  const int wv = tid >> 6, ln = tid & 63;
  const int wr = wv >> 1, wc = wv & 1;              // 4 x 2 wave grid
  const int g = ln >> 4, rl = ln & 15;
  const int colswz = (rl & 7) << 4;                 // A read-side 3-bit XOR

  // XCD-aware block swizzle (nwg % 8 == 0 for all grids used)
  const int nwg = gridDim.x * gridDim.y;
  int lbid = blockIdx.y * gridDim.x + blockIdx.x;
  lbid = (lbid & 7) * (nwg >> 3) + (lbid >> 3);
  const int bn = lbid % gridDim.x, bm = lbid / gridDim.x;

  const signed char* Abase = A + (size_t)bm * 256 * K;
  const signed char* Wpb = (const signed char*)(Wp + (size_t)bn * 128);

  // ---- hoisted per-lane constants ----
  const int myAoff = wr * 8192;
  const int bcol = wc * 64;
  const int aoff0 = myAoff + rl * 128 + ((g * 16) ^ colswz);          // ks=0
  const int aoff1 = myAoff + rl * 128 + ((64 + g * 16) ^ colswz);     // ks=1
  const int bswz = (g & 1) << 6;
  const int boffB = 32768 + g * 512 + 4 * (bcol + rl);
  int be[4];
  #pragma unroll
  for (int np = 0; np < 4; ++np) be[np] = boffB + ((np * 64) ^ bswz);
  int srcA[4], dstA[4];
  #pragma unroll
  for (int i = 0; i < 4; ++i) {
    const int c = tid + 512 * i;
    srcA[i] = (c >> 3) * K + ((c ^ (c >> 3)) & 7) * 16;
    dstA[i] = c * 16;
  }
  const int kcs = tid >> 5, js = tid & 31;          // B-stage role (wv<4)
  const size_t srcB = (size_t)kcs * N * 4 + 4 * ((4 * js) ^ ((kcs & 1) << 4));
  const int dstB = 32768 + kcs * 512 + js * 16;

  auto stage = [&](int tt) {
    if (tt >= NT) return;
    signed char* dA = lds + (tt & 1) * BUFSZ;
    const signed char* sA = Abase + tt * 128;
    #pragma unroll
    for (int i = 0; i < 4; ++i) GLDS16(sA + srcA[i], dA + dstA[i]);
    if (wv < 4)
      GLDS16(Wpb + (size_t)tt * (N * 32) + srcB, dA + dstB);
  };

  i32x4_t acc[4][4];
  #pragma unroll
  for (int m = 0; m < 4; ++m)
    #pragma unroll
    for (int n = 0; n < 4; ++n) acc[m][n] = (i32x4_t){0, 0, 0, 0};

  // prologue
  stage(0); stage(1);
  asm volatile("s_waitcnt vmcnt(4)" ::: "memory");
  __builtin_amdgcn_s_barrier();

  for (int t = 0; t < NT; ++t) {
    const signed char* bufb = lds + (t & 1) * BUFSZ;
    const signed char* pa0 = bufb + aoff0;
    const signed char* pa1 = bufb + aoff1;

    unsigned int bp[2][4];
    #pragma unroll
    for (int ks = 0; ks < 2; ++ks)
      #pragma unroll
      for (int np = 0; np < 4; ++np)
        bp[ks][np] = *(const unsigned int*)(bufb + be[np] + ks * 2048);

    __builtin_amdgcn_s_setprio(1);
    #pragma unroll
    for (int ks = 0; ks < 2; ++ks) {
      i32x4_t bu[4];
      #pragma unroll
      for (int np = 0; np < 4; ++np)
        #pragma unroll
        for (int j = 0; j < 4; ++j)
          bu[np][j] = (int)((bp[ks][np] >> (2 * j)) & 0x03030303u);
      const signed char* pa = ks ? pa1 : pa0;
      #pragma unroll
      for (int m = 0; m < 4; ++m) {
        const i32x4_t af = *(const i32x4_t*)(pa + m * 2048);
        #pragma unroll
        for (int np = 0; np < 4; ++np)
          acc[m][np] = __builtin_amdgcn_mfma_i32_16x16x64_i8(
              af, bu[np], acc[m][np], 0, 0, 0);
      }
    }
    __builtin_amdgcn_s_setprio(0);

    asm volatile("s_waitcnt lgkmcnt(0)" ::: "memory");
    __builtin_amdgcn_s_barrier();            // all waves done reading buf[cur]
    stage(t + 2);                            // refill buf[cur] with tile t+2
    if (t + 2 < NT) asm volatile("s_waitcnt vmcnt(4)" ::: "memory");
    else            asm volatile("s_waitcnt vmcnt(0)" ::: "memory");
    __builtin_amdgcn_s_barrier();            // tile t+1 confirmed resident
  }

  // -------- epilogue: undo weight bias, scale, bias, fast tanh --------------
  const float invw = wsc[widx * 2 + 1];
  const int row0 = bm * 256 + wr * 64;
  const int col0 = bn * 128 + wc * 64;
  #pragma unroll
  for (int m = 0; m < 4; ++m) {
    #pragma unroll
    for (int r = 0; r < 4; ++r) {
      const int gb = row0 + m * 16 + g * 4 + r;
      const float fa = inv_sa[gb] * invw;
      const int sr = rsum[gb];
      #pragma unroll
      for (int np = 0; np < 4; ++np) {
        const int go = col0 + np * 16 + rl;
        const float v = (float)(acc[m][np][r] - sr) * fa + bias[go];
        float rres;
        if (TANH) {
          // tanh(x) = 1 - 2/(e^{2x}+1); saturates to +-1, no NaN
          const float e2 = __expf(2.f * v);
          rres = 1.f - 2.f * __builtin_amdgcn_rcpf(e2 + 1.f);
        } else {
          rres = v;
        }
        out[(size_t)gb * N + go] = rres;
      }
    }
  }
}

// ---------------- driver ----------------------------------------------------
extern "C" void kernel_launch(void* const* d_in, const int* in_sizes, int n_in,
                              void* d_out, int out_size, void* d_ws, size_t ws_size,
                              hipStream_t stream)
{
  const float* x  = (const float*)d_in[0];
  const float* w1 = (const float*)d_in[1]; const float* b1 = (const float*)d_in[2];
  const float* w2 = (const float*)d_in[3]; const float* b2 = (const float*)d_in[4];
  const float* w3 = (const float*)d_in[5]; const float* b3 = (const float*)d_in[6];
  const float* w4 = (const float*)d_in[7]; const float* b4 = (const float*)d_in[8];
  float* out = (float*)d_out;

  constexpr int B = 8192, DIN = 1024, H = 4096, DOUT = 1024;
  char* ws = (char*)d_ws;
  size_t off = 0;
  float*        hbuf = (float*)(ws + off);        off += (size_t)B * H * 4;
  signed char*  xq   = (signed char*)(ws + off);  off += (size_t)B * H;
  unsigned int* wp1  = (unsigned int*)(ws + off); off += (size_t)(DIN / 16) * H * 4;
  unsigned int* wp2  = (unsigned int*)(ws + off); off += (size_t)(H / 16) * H * 4;
  unsigned int* wp3  = (unsigned int*)(ws + off); off += (size_t)(H / 16) * H * 4;
  unsigned int* wp4  = (unsigned int*)(ws + off); off += (size_t)(H / 16) * DOUT * 4;
  float*        inv_sa = (float*)(ws + off);      off += (size_t)B * 4;
  int*          rsum = (int*)(ws + off);          off += (size_t)B * 4;
  double*       part = (double*)(ws + off);       off += 1280 * 8;
  float*        wsc  = (float*)(ws + off);        off += 64;

  // weight prep: 2 + 1 launches for all four tensors
  absmean4_part_k<<<1280, 256, 0, stream>>>(w1, w2, w3, w4, part);
  absmean4_fin_k<<<1, 256, 0, stream>>>(part, wsc);
  quant_w_pack4_k<<<10240, 256, 0, stream>>>(w1, w2, w3, w4,
                                             wp1, wp2, wp3, wp4, wsc);

  // layer 1: K=DIN=1024, N=H
  act_quant_k<DIN><<<B, 256, 0, stream>>>(x, (unsigned int*)xq, inv_sa, rsum);
  gemm2p<DIN, H, true><<<dim3(H / 128, B / 256), 512, 0, stream>>>(
      xq, wp1, inv_sa, rsum, wsc, 0, b1, hbuf);

  // layer 2: K=H, N=H
  act_quant_k<H><<<B, 256, 0, stream>>>(hbuf, (unsigned int*)xq, inv_sa, rsum);
  gemm2p<H, H, true><<<dim3(H / 128, B / 256), 512, 0, stream>>>(
      xq, wp2, inv_sa, rsum, wsc, 1, b2, hbuf);

  // layer 3: K=H, N=H
  act_quant_k<H><<<B, 256, 0, stream>>>(hbuf, (unsigned int*)xq, inv_sa, rsum);
  gemm2p<H, H, true><<<dim3(H / 128, B / 256), 512, 0, stream>>>(
      xq, wp3, inv_sa, rsum, wsc, 2, b3, hbuf);

  // layer 4: K=H, N=DOUT, no tanh
  act_quant_k<H><<<B, 256, 0, stream>>>(hbuf, (unsigned int*)xq, inv_sa, rsum);
  gemm2p<H, DOUT, false><<<dim3(DOUT / 128, B / 256), 512, 0, stream>>>(
      xq, wp4, inv_sa, rsum, wsc, 3, b4, out);
}

// Round 15
// 474.760 us; speedup vs baseline: 8.1444x; 1.0151x over previous
//
#include <hip/hip_runtime.h>
#include <hip/hip_bf16.h>

// BitNet 4-layer MLP forward, MI355X — round 15: templated BM; L4 on BM=128.
// r14's L4 grid = 256 blocks = 1 block/CU (2 waves/SIMD) = r6 stall regime.
// BM=128 tile: BUFSZ 20KB, dbuf 40KB -> 4 blocks/CU co-residency for L4.
// L1-L3 unchanged (BM=256, proven 145us for L2/L3).

typedef __attribute__((ext_vector_type(4))) int i32x4_t;

#define GLDS16(g, l) __builtin_amdgcn_global_load_lds( \
    (const __attribute__((address_space(1))) unsigned int*)(g), \
    (__attribute__((address_space(3))) unsigned int*)(l), 16, 0, 0)

// ---------------- merged weight abs-mean: one pass over all 4 tensors -------
__global__ __launch_bounds__(256) void absmean4_part_k(
    const float* __restrict__ w1, const float* __restrict__ w2,
    const float* __restrict__ w3, const float* __restrict__ w4,
    double* __restrict__ part)
{
  const int b = blockIdx.x;
  const float* W; int n4, b0, nb;
  if (b < 128)       { W = w1; n4 = 1 << 20; b0 = 0;    nb = 128; }
  else if (b < 640)  { W = w2; n4 = 1 << 22; b0 = 128;  nb = 512; }
  else if (b < 1152) { W = w3; n4 = 1 << 22; b0 = 640;  nb = 512; }
  else               { W = w4; n4 = 1 << 20; b0 = 1152; nb = 128; }
  double s = 0.0;
  const int stride = nb * 256;
  for (int i = (b - b0) * 256 + threadIdx.x; i < n4; i += stride) {
    float4 v = ((const float4*)W)[i];
    s += (double)fabsf(v.x); s += (double)fabsf(v.y);
    s += (double)fabsf(v.z); s += (double)fabsf(v.w);
  }
  __shared__ double sd[256];
  sd[threadIdx.x] = s;
  __syncthreads();
  for (int st = 128; st > 0; st >>= 1) {
    if (threadIdx.x < st) sd[threadIdx.x] += sd[threadIdx.x + st];
    __syncthreads();
  }
  if (threadIdx.x == 0) part[b] = sd[0];
}

__global__ __launch_bounds__(256) void absmean4_fin_k(
    const double* __restrict__ part, float* __restrict__ wsc)
{
  __shared__ double sd[256];
  const int tid = threadIdx.x;
  const int seg[5] = {0, 128, 640, 1152, 1280};
  const double nel[4] = {4194304.0, 16777216.0, 16777216.0, 4194304.0};
  for (int si = 0; si < 4; ++si) {
    double s = 0.0;
    for (int i = seg[si] + tid; i < seg[si + 1]; i += 256) s += part[i];
    sd[tid] = s;
    __syncthreads();
    for (int st = 128; st > 0; st >>= 1) {
      if (tid < st) sd[tid] += sd[tid + st];
      __syncthreads();
    }
    if (tid == 0) {
      float mean = (float)(sd[0] / nel[si]);
      float scale = 1.f / fmaxf(mean, 1e-5f);
      wsc[si * 2]     = scale;
      wsc[si * 2 + 1] = 1.f / scale;
    }
    __syncthreads();
  }
}

// ------- merged weight pack (biased {0,1,2} 2-bit), float4-vectorized -------
__global__ __launch_bounds__(256) void quant_w_pack4_k(
    const float* __restrict__ w1, const float* __restrict__ w2,
    const float* __restrict__ w3, const float* __restrict__ w4,
    unsigned int* __restrict__ wp1, unsigned int* __restrict__ wp2,
    unsigned int* __restrict__ wp3, unsigned int* __restrict__ wp4,
    const float* __restrict__ wsc)
{
  int idx = blockIdx.x * 256 + threadIdx.x;
  const float* W; unsigned int* Wp; int Kd, Nd, widx;
  if (idx < 262144)        { W = w1; Wp = wp1; Kd = 1024; Nd = 4096; widx = 0; }
  else if (idx < 1310720)  { idx -= 262144;  W = w2; Wp = wp2; Kd = 4096; Nd = 4096; widx = 1; }
  else if (idx < 2359296)  { idx -= 1310720; W = w3; Wp = wp3; Kd = 4096; Nd = 4096; widx = 2; }
  else                     { idx -= 2359296; W = w4; Wp = wp4; Kd = 4096; Nd = 1024; widx = 3; }
  const float s = wsc[widx * 2];
  const int kc = idx & (Kd / 16 - 1);
  const int o  = idx / (Kd / 16);
  const float4* wr = (const float4*)(W + (size_t)o * Kd + kc * 16);
  unsigned int u = 0;
  #pragma unroll
  for (int q4 = 0; q4 < 4; ++q4) {
    const float4 v = wr[q4];
    int q;
    q = (int)fminf(fmaxf(rintf(v.x * s), -1.f), 1.f); u |= (unsigned int)(q + 1) << (2 * q4);
    q = (int)fminf(fmaxf(rintf(v.y * s), -1.f), 1.f); u |= (unsigned int)(q + 1) << (8 + 2 * q4);
    q = (int)fminf(fmaxf(rintf(v.z * s), -1.f), 1.f); u |= (unsigned int)(q + 1) << (16 + 2 * q4);
    q = (int)fminf(fmaxf(rintf(v.w * s), -1.f), 1.f); u |= (unsigned int)(q + 1) << (24 + 2 * q4);
  }
  Wp[(size_t)kc * Nd + o] = u;
}

// ---------------- per-row activation quantization to i8 + row-sum -----------
template<int D>
__global__ __launch_bounds__(256) void act_quant_k(
    const float* __restrict__ X, unsigned int* __restrict__ Xq,
    float* __restrict__ inv_sa, int* __restrict__ rsum)
{
  constexpr int PER = D / 1024;
  const int row = blockIdx.x, tid = threadIdx.x;
  const float4* xr = (const float4*)(X + (size_t)row * D);
  float4 v[PER];
  float m = 0.f;
  #pragma unroll
  for (int i = 0; i < PER; ++i) {
    v[i] = xr[tid + 256 * i];
    m = fmaxf(m, fmaxf(fmaxf(fabsf(v[i].x), fabsf(v[i].y)),
                       fmaxf(fabsf(v[i].z), fabsf(v[i].w))));
  }
  #pragma unroll
  for (int off = 32; off >= 1; off >>= 1) m = fmaxf(m, __shfl_xor(m, off));
  __shared__ float wm[4];
  if ((tid & 63) == 0) wm[tid >> 6] = m;
  __syncthreads();
  m = fmaxf(fmaxf(wm[0], wm[1]), fmaxf(wm[2], wm[3]));
  const float s = 127.f / fmaxf(m, 1e-5f);
  if (tid == 0) inv_sa[row] = 1.f / s;
  unsigned int* oq = Xq + (size_t)row * (D / 4);
  int isum = 0;
  #pragma unroll
  for (int i = 0; i < PER; ++i) {
    const int qx = (int)fminf(fmaxf(rintf(v[i].x * s), -128.f), 127.f);
    const int qy = (int)fminf(fmaxf(rintf(v[i].y * s), -128.f), 127.f);
    const int qz = (int)fminf(fmaxf(rintf(v[i].z * s), -128.f), 127.f);
    const int qw = (int)fminf(fmaxf(rintf(v[i].w * s), -128.f), 127.f);
    isum += qx + qy + qz + qw;
    oq[tid + 256 * i] = (unsigned int)(qx & 255) | ((unsigned int)(qy & 255) << 8)
                      | ((unsigned int)(qz & 255) << 16) | ((unsigned int)(qw & 255) << 24);
  }
  #pragma unroll
  for (int off = 32; off >= 1; off >>= 1) isum += __shfl_xor(isum, off);
  __shared__ int wsum[4];
  if ((tid & 63) == 0) wsum[tid >> 6] = isum;
  __syncthreads();
  if (tid == 0) rsum[row] = wsum[0] + wsum[1] + wsum[2] + wsum[3];
}

// ---- BMx128 dbuf i8-A / 2-bit-biased-B GEMM (BM in {256,128}) --------------
// 8 waves: (BM/64) M-waves x NW N-waves; per-wave 64 x (128/NW) cols.
// BM=256: BUFSZ 36864, 2 blocks/CU, vmcnt(4). BM=128: BUFSZ 20480,
// up to 4 blocks/CU, vmcnt(2). Swizzles identical to r14 (verified).
template<int BM, int K, int N, bool TANH>
__global__ __launch_bounds__(512, 4) void gemm2p(
    const signed char* __restrict__ A, const unsigned int* __restrict__ Wp,
    const float* __restrict__ inv_sa, const int* __restrict__ rsum,
    const float* __restrict__ wsc, int widx,
    const float* __restrict__ bias, float* __restrict__ out)
{
  constexpr int MW   = BM / 64;          // M-waves
  constexpr int NW   = 8 / MW;           // N-waves
  constexpr int LNW  = (NW == 2) ? 1 : 2;
  constexpr int PC   = 128 / NW;         // per-wave cols
  constexpr int NPL  = PC / 16;          // np loop extent
  constexpr int NAG  = BM / 64;          // per-thread A-stage GLDS
  constexpr int BOFF = BM * 128;         // B region start in buffer
  constexpr int BUFSZ = BM * 128 + 4096;
  __shared__ __align__(16) signed char lds[2 * BUFSZ];
  constexpr int NT = K / 128;
  const int tid = threadIdx.x;
  const int wv = tid >> 6, ln = tid & 63;
  const int wr = wv >> LNW, wc = wv & (NW - 1);
  const int g = ln >> 4, rl = ln & 15;
  const int colswz = (rl & 7) << 4;

  // XCD-aware block swizzle (nwg % 8 == 0 for all grids used)
  const int nwg = gridDim.x * gridDim.y;
  int lbid = blockIdx.y * gridDim.x + blockIdx.x;
  lbid = (lbid & 7) * (nwg >> 3) + (lbid >> 3);
  const int bn = lbid % gridDim.x, bm = lbid / gridDim.x;

  const signed char* Abase = A + (size_t)bm * BM * K;
  const signed char* Wpb = (const signed char*)(Wp + (size_t)bn * 128);

  // ---- hoisted per-lane constants ----
  const int myAoff = wr * 8192;                       // 64 rows * 128B
  const int bcol = wc * PC;
  const int aoff0 = myAoff + rl * 128 + ((g * 16) ^ colswz);
  const int aoff1 = myAoff + rl * 128 + ((64 + g * 16) ^ colswz);
  const int bswz = (g & 1) << 6;
  const int boffB = BOFF + g * 512 + 4 * (bcol + rl);
  int be[NPL];
  #pragma unroll
  for (int np = 0; np < NPL; ++np) be[np] = boffB + ((np * 64) ^ bswz);
  int srcA[NAG], dstA[NAG];
  #pragma unroll
  for (int i = 0; i < NAG; ++i) {
    const int c = tid + 512 * i;
    srcA[i] = (c >> 3) * K + ((c ^ (c >> 3)) & 7) * 16;
    dstA[i] = c * 16;
  }
  const int kcs = tid >> 5, js = tid & 31;            // B-stage role (wv<4)
  const size_t srcB = (size_t)kcs * N * 4 + 4 * ((4 * js) ^ ((kcs & 1) << 4));
  const int dstB = BOFF + kcs * 512 + js * 16;

  auto stage = [&](int tt) {
    if (tt >= NT) return;
    signed char* dA = lds + (tt & 1) * BUFSZ;
    const signed char* sA = Abase + tt * 128;
    #pragma unroll
    for (int i = 0; i < NAG; ++i) GLDS16(sA + srcA[i], dA + dstA[i]);
    if (wv < 4)
      GLDS16(Wpb + (size_t)tt * (N * 32) + srcB, dA + dstB);
  };

  i32x4_t acc[4][NPL];
  #pragma unroll
  for (int m = 0; m < 4; ++m)
    #pragma unroll
    for (int n = 0; n < NPL; ++n) acc[m][n] = (i32x4_t){0, 0, 0, 0};

  // prologue
  stage(0); stage(1);
  if constexpr (BM == 256) asm volatile("s_waitcnt vmcnt(4)" ::: "memory");
  else                     asm volatile("s_waitcnt vmcnt(2)" ::: "memory");
  __builtin_amdgcn_s_barrier();

  for (int t = 0; t < NT; ++t) {
    const signed char* bufb = lds + (t & 1) * BUFSZ;
    const signed char* pa0 = bufb + aoff0;
    const signed char* pa1 = bufb + aoff1;

    unsigned int bp[2][NPL];
    #pragma unroll
    for (int ks = 0; ks < 2; ++ks)
      #pragma unroll
      for (int np = 0; np < NPL; ++np)
        bp[ks][np] = *(const unsigned int*)(bufb + be[np] + ks * 2048);

    __builtin_amdgcn_s_setprio(1);
    #pragma unroll
    for (int ks = 0; ks < 2; ++ks) {
      i32x4_t bu[NPL];
      #pragma unroll
      for (int np = 0; np < NPL; ++np)
        #pragma unroll
        for (int j = 0; j < 4; ++j)
          bu[np][j] = (int)((bp[ks][np] >> (2 * j)) & 0x03030303u);
      const signed char* pa = ks ? pa1 : pa0;
      #pragma unroll
      for (int m = 0; m < 4; ++m) {
        const i32x4_t af = *(const i32x4_t*)(pa + m * 2048);
        #pragma unroll
        for (int np = 0; np < NPL; ++np)
          acc[m][np] = __builtin_amdgcn_mfma_i32_16x16x64_i8(
              af, bu[np], acc[m][np], 0, 0, 0);
      }
    }
    __builtin_amdgcn_s_setprio(0);

    asm volatile("s_waitcnt lgkmcnt(0)" ::: "memory");
    __builtin_amdgcn_s_barrier();            // all waves done reading buf[cur]
    stage(t + 2);                            // refill buf[cur] with tile t+2
    if (t + 2 < NT) {
      if constexpr (BM == 256) asm volatile("s_waitcnt vmcnt(4)" ::: "memory");
      else                     asm volatile("s_waitcnt vmcnt(2)" ::: "memory");
    } else {
      asm volatile("s_waitcnt vmcnt(0)" ::: "memory");
    }
    __builtin_amdgcn_s_barrier();            // tile t+1 confirmed resident
  }

  // -------- epilogue: undo weight bias, scale, bias, fast tanh --------------
  const float invw = wsc[widx * 2 + 1];
  const int row0 = bm * BM + wr * 64;
  const int col0 = bn * 128 + wc * PC;
  #pragma unroll
  for (int m = 0; m < 4; ++m) {
    #pragma unroll
    for (int r = 0; r < 4; ++r) {
      const int gb = row0 + m * 16 + g * 4 + r;
      const float fa = inv_sa[gb] * invw;
      const int sr = rsum[gb];
      #pragma unroll
      for (int np = 0; np < NPL; ++np) {
        const int go = col0 + np * 16 + rl;
        const float v = (float)(acc[m][np][r] - sr) * fa + bias[go];
        float rres;
        if (TANH) {
          const float e2 = __expf(2.f * v);
          rres = 1.f - 2.f * __builtin_amdgcn_rcpf(e2 + 1.f);
        } else {
          rres = v;
        }
        out[(size_t)gb * N + go] = rres;
      }
    }
  }
}

// ---------------- driver ----------------------------------------------------
extern "C" void kernel_launch(void* const* d_in, const int* in_sizes, int n_in,
                              void* d_out, int out_size, void* d_ws, size_t ws_size,
                              hipStream_t stream)
{
  const float* x  = (const float*)d_in[0];
  const float* w1 = (const float*)d_in[1]; const float* b1 = (const float*)d_in[2];
  const float* w2 = (const float*)d_in[3]; const float* b2 = (const float*)d_in[4];
  const float* w3 = (const float*)d_in[5]; const float* b3 = (const float*)d_in[6];
  const float* w4 = (const float*)d_in[7]; const float* b4 = (const float*)d_in[8];
  float* out = (float*)d_out;

  constexpr int B = 8192, DIN = 1024, H = 4096, DOUT = 1024;
  char* ws = (char*)d_ws;
  size_t off = 0;
  float*        hbuf = (float*)(ws + off);        off += (size_t)B * H * 4;
  signed char*  xq   = (signed char*)(ws + off);  off += (size_t)B * H;
  unsigned int* wp1  = (unsigned int*)(ws + off); off += (size_t)(DIN / 16) * H * 4;
  unsigned int* wp2  = (unsigned int*)(ws + off); off += (size_t)(H / 16) * H * 4;
  unsigned int* wp3  = (unsigned int*)(ws + off); off += (size_t)(H / 16) * H * 4;
  unsigned int* wp4  = (unsigned int*)(ws + off); off += (size_t)(H / 16) * DOUT * 4;
  float*        inv_sa = (float*)(ws + off);      off += (size_t)B * 4;
  int*          rsum = (int*)(ws + off);          off += (size_t)B * 4;
  double*       part = (double*)(ws + off);       off += 1280 * 8;
  float*        wsc  = (float*)(ws + off);        off += 64;

  // weight prep: 3 launches for all four tensors
  absmean4_part_k<<<1280, 256, 0, stream>>>(w1, w2, w3, w4, part);
  absmean4_fin_k<<<1, 256, 0, stream>>>(part, wsc);
  quant_w_pack4_k<<<10240, 256, 0, stream>>>(w1, w2, w3, w4,
                                             wp1, wp2, wp3, wp4, wsc);

  // layer 1: K=DIN=1024, N=H (BM=256, 1024 blocks, 2/CU)
  act_quant_k<DIN><<<B, 256, 0, stream>>>(x, (unsigned int*)xq, inv_sa, rsum);
  gemm2p<256, DIN, H, true><<<dim3(H / 128, B / 256), 512, 0, stream>>>(
      xq, wp1, inv_sa, rsum, wsc, 0, b1, hbuf);

  // layer 2: K=H, N=H
  act_quant_k<H><<<B, 256, 0, stream>>>(hbuf, (unsigned int*)xq, inv_sa, rsum);
  gemm2p<256, H, H, true><<<dim3(H / 128, B / 256), 512, 0, stream>>>(
      xq, wp2, inv_sa, rsum, wsc, 1, b2, hbuf);

  // layer 3: K=H, N=H
  act_quant_k<H><<<B, 256, 0, stream>>>(hbuf, (unsigned int*)xq, inv_sa, rsum);
  gemm2p<256, H, H, true><<<dim3(H / 128, B / 256), 512, 0, stream>>>(
      xq, wp3, inv_sa, rsum, wsc, 2, b3, hbuf);

  // layer 4: K=H, N=DOUT, no tanh — BM=128: 512 blocks, 4/CU co-residency
  act_quant_k<H><<<B, 256, 0, stream>>>(hbuf, (unsigned int*)xq, inv_sa, rsum);
  gemm2p<128, H, DOUT, false><<<dim3(DOUT / 128, B / 128), 512, 0, stream>>>(
      xq, wp4, inv_sa, rsum, wsc, 3, b4, out);
}

// Round 16
// 441.968 us; speedup vs baseline: 8.7486x; 1.0742x over previous
//
#include <hip/hip_runtime.h>
#include <hip/hip_bf16.h>

// BitNet 4-layer MLP forward, MI355X — round 16: int16 (q15) inter-layer h.
// hbuf fp32 round-trip (128MB write + 128MB read per boundary) was ~120us of
// BW. tanh in [-1,1] -> store q15 int16 (scale 32767): halves both sides.
// Storage step 3e-5 -> added error ~3e-4 vs 2.1e-3 margin. GEMM loop untouched.

typedef __attribute__((ext_vector_type(4))) int i32x4_t;

#define GLDS16(g, l) __builtin_amdgcn_global_load_lds( \
    (const __attribute__((address_space(1))) unsigned int*)(g), \
    (__attribute__((address_space(3))) unsigned int*)(l), 16, 0, 0)

// ---------------- merged weight abs-mean: one pass over all 4 tensors -------
__global__ __launch_bounds__(256) void absmean4_part_k(
    const float* __restrict__ w1, const float* __restrict__ w2,
    const float* __restrict__ w3, const float* __restrict__ w4,
    double* __restrict__ part)
{
  const int b = blockIdx.x;
  const float* W; int n4, b0, nb;
  if (b < 128)       { W = w1; n4 = 1 << 20; b0 = 0;    nb = 128; }
  else if (b < 640)  { W = w2; n4 = 1 << 22; b0 = 128;  nb = 512; }
  else if (b < 1152) { W = w3; n4 = 1 << 22; b0 = 640;  nb = 512; }
  else               { W = w4; n4 = 1 << 20; b0 = 1152; nb = 128; }
  double s = 0.0;
  const int stride = nb * 256;
  for (int i = (b - b0) * 256 + threadIdx.x; i < n4; i += stride) {
    float4 v = ((const float4*)W)[i];
    s += (double)fabsf(v.x); s += (double)fabsf(v.y);
    s += (double)fabsf(v.z); s += (double)fabsf(v.w);
  }
  __shared__ double sd[256];
  sd[threadIdx.x] = s;
  __syncthreads();
  for (int st = 128; st > 0; st >>= 1) {
    if (threadIdx.x < st) sd[threadIdx.x] += sd[threadIdx.x + st];
    __syncthreads();
  }
  if (threadIdx.x == 0) part[b] = sd[0];
}

__global__ __launch_bounds__(256) void absmean4_fin_k(
    const double* __restrict__ part, float* __restrict__ wsc)
{
  __shared__ double sd[256];
  const int tid = threadIdx.x;
  const int seg[5] = {0, 128, 640, 1152, 1280};
  const double nel[4] = {4194304.0, 16777216.0, 16777216.0, 4194304.0};
  for (int si = 0; si < 4; ++si) {
    double s = 0.0;
    for (int i = seg[si] + tid; i < seg[si + 1]; i += 256) s += part[i];
    sd[tid] = s;
    __syncthreads();
    for (int st = 128; st > 0; st >>= 1) {
      if (tid < st) sd[tid] += sd[tid + st];
      __syncthreads();
    }
    if (tid == 0) {
      float mean = (float)(sd[0] / nel[si]);
      float scale = 1.f / fmaxf(mean, 1e-5f);
      wsc[si * 2]     = scale;
      wsc[si * 2 + 1] = 1.f / scale;
    }
    __syncthreads();
  }
}

// ------- merged weight pack (biased {0,1,2} 2-bit), float4-vectorized -------
__global__ __launch_bounds__(256) void quant_w_pack4_k(
    const float* __restrict__ w1, const float* __restrict__ w2,
    const float* __restrict__ w3, const float* __restrict__ w4,
    unsigned int* __restrict__ wp1, unsigned int* __restrict__ wp2,
    unsigned int* __restrict__ wp3, unsigned int* __restrict__ wp4,
    const float* __restrict__ wsc)
{
  int idx = blockIdx.x * 256 + threadIdx.x;
  const float* W; unsigned int* Wp; int Kd, Nd, widx;
  if (idx < 262144)        { W = w1; Wp = wp1; Kd = 1024; Nd = 4096; widx = 0; }
  else if (idx < 1310720)  { idx -= 262144;  W = w2; Wp = wp2; Kd = 4096; Nd = 4096; widx = 1; }
  else if (idx < 2359296)  { idx -= 1310720; W = w3; Wp = wp3; Kd = 4096; Nd = 4096; widx = 2; }
  else                     { idx -= 2359296; W = w4; Wp = wp4; Kd = 4096; Nd = 1024; widx = 3; }
  const float s = wsc[widx * 2];
  const int kc = idx & (Kd / 16 - 1);
  const int o  = idx / (Kd / 16);
  const float4* wr = (const float4*)(W + (size_t)o * Kd + kc * 16);
  unsigned int u = 0;
  #pragma unroll
  for (int q4 = 0; q4 < 4; ++q4) {
    const float4 v = wr[q4];
    int q;
    q = (int)fminf(fmaxf(rintf(v.x * s), -1.f), 1.f); u |= (unsigned int)(q + 1) << (2 * q4);
    q = (int)fminf(fmaxf(rintf(v.y * s), -1.f), 1.f); u |= (unsigned int)(q + 1) << (8 + 2 * q4);
    q = (int)fminf(fmaxf(rintf(v.z * s), -1.f), 1.f); u |= (unsigned int)(q + 1) << (16 + 2 * q4);
    q = (int)fminf(fmaxf(rintf(v.w * s), -1.f), 1.f); u |= (unsigned int)(q + 1) << (24 + 2 * q4);
  }
  Wp[(size_t)kc * Nd + o] = u;
}

// -------- per-row activation quantization to i8 + row-sum (fp32/q15 in) -----
template<int D, bool IN16>
__global__ __launch_bounds__(256) void act_quant_k(
    const void* __restrict__ Xv, unsigned int* __restrict__ Xq,
    float* __restrict__ inv_sa, int* __restrict__ rsum)
{
  constexpr int PT = D / 256;                // values per thread
  const int row = blockIdx.x, tid = threadIdx.x;
  float xv[PT];
  if constexpr (IN16) {
    const uint4* xr = (const uint4*)((const short*)Xv + (size_t)row * D);
    #pragma unroll
    for (int i = 0; i < PT / 8; ++i) {
      const uint4 u = xr[tid + 256 * i];
      const unsigned int w[4] = {u.x, u.y, u.z, u.w};
      #pragma unroll
      for (int j = 0; j < 4; ++j) {
        xv[i * 8 + 2 * j]     = (float)(short)(w[j] & 0xffffu) * (1.f / 32767.f);
        xv[i * 8 + 2 * j + 1] = (float)(short)(w[j] >> 16)     * (1.f / 32767.f);
      }
    }
  } else {
    const float4* xr = (const float4*)((const float*)Xv + (size_t)row * D);
    #pragma unroll
    for (int i = 0; i < PT / 4; ++i) {
      const float4 v = xr[tid + 256 * i];
      xv[i * 4] = v.x; xv[i * 4 + 1] = v.y;
      xv[i * 4 + 2] = v.z; xv[i * 4 + 3] = v.w;
    }
  }
  float m = 0.f;
  #pragma unroll
  for (int i = 0; i < PT; ++i) m = fmaxf(m, fabsf(xv[i]));
  #pragma unroll
  for (int off = 32; off >= 1; off >>= 1) m = fmaxf(m, __shfl_xor(m, off));
  __shared__ float wm[4];
  if ((tid & 63) == 0) wm[tid >> 6] = m;
  __syncthreads();
  m = fmaxf(fmaxf(wm[0], wm[1]), fmaxf(wm[2], wm[3]));
  const float s = 127.f / fmaxf(m, 1e-5f);
  if (tid == 0) inv_sa[row] = 1.f / s;
  unsigned int* oq = Xq + (size_t)row * (D / 4);
  int isum = 0;
  #pragma unroll
  for (int di = 0; di < PT / 4; ++di) {
    int q[4];
    #pragma unroll
    for (int e = 0; e < 4; ++e) {
      q[e] = (int)fminf(fmaxf(rintf(xv[di * 4 + e] * s), -128.f), 127.f);
      isum += q[e];
    }
    const unsigned int pk =
        (unsigned int)(q[0] & 255) | ((unsigned int)(q[1] & 255) << 8) |
        ((unsigned int)(q[2] & 255) << 16) | ((unsigned int)(q[3] & 255) << 24);
    // global dword index covering k = 4*gd .. 4*gd+3
    int gd;
    if constexpr (IN16) gd = 2 * (tid + 256 * (di / 2)) + (di & 1);
    else                gd = tid + 256 * di;
    oq[gd] = pk;
  }
  #pragma unroll
  for (int off = 32; off >= 1; off >>= 1) isum += __shfl_xor(isum, off);
  __shared__ int wsum[4];
  if ((tid & 63) == 0) wsum[tid >> 6] = isum;
  __syncthreads();
  if (tid == 0) rsum[row] = wsum[0] + wsum[1] + wsum[2] + wsum[3];
}

// ---- BMx128 dbuf i8-A / 2-bit-biased-B GEMM (BM in {256,128}) --------------
// TANH layers store q15 int16 h (scale 32767); final layer stores fp32.
template<int BM, int K, int N, bool TANH>
__global__ __launch_bounds__(512, 4) void gemm2p(
    const signed char* __restrict__ A, const unsigned int* __restrict__ Wp,
    const float* __restrict__ inv_sa, const int* __restrict__ rsum,
    const float* __restrict__ wsc, int widx,
    const float* __restrict__ bias, void* __restrict__ outv)
{
  constexpr int MW   = BM / 64;
  constexpr int NW   = 8 / MW;
  constexpr int LNW  = (NW == 2) ? 1 : 2;
  constexpr int PC   = 128 / NW;
  constexpr int NPL  = PC / 16;
  constexpr int NAG  = BM / 64;
  constexpr int BOFF = BM * 128;
  constexpr int BUFSZ = BM * 128 + 4096;
  __shared__ __align__(16) signed char lds[2 * BUFSZ];
  constexpr int NT = K / 128;
  const int tid = threadIdx.x;
  const int wv = tid >> 6, ln = tid & 63;
  const int wr = wv >> LNW, wc = wv & (NW - 1);
  const int g = ln >> 4, rl = ln & 15;
  const int colswz = (rl & 7) << 4;

  // XCD-aware block swizzle (nwg % 8 == 0 for all grids used)
  const int nwg = gridDim.x * gridDim.y;
  int lbid = blockIdx.y * gridDim.x + blockIdx.x;
  lbid = (lbid & 7) * (nwg >> 3) + (lbid >> 3);
  const int bn = lbid % gridDim.x, bm = lbid / gridDim.x;

  const signed char* Abase = A + (size_t)bm * BM * K;
  const signed char* Wpb = (const signed char*)(Wp + (size_t)bn * 128);

  // ---- hoisted per-lane constants ----
  const int myAoff = wr * 8192;
  const int bcol = wc * PC;
  const int aoff0 = myAoff + rl * 128 + ((g * 16) ^ colswz);
  const int aoff1 = myAoff + rl * 128 + ((64 + g * 16) ^ colswz);
  const int bswz = (g & 1) << 6;
  const int boffB = BOFF + g * 512 + 4 * (bcol + rl);
  int be[NPL];
  #pragma unroll
  for (int np = 0; np < NPL; ++np) be[np] = boffB + ((np * 64) ^ bswz);
  int srcA[NAG], dstA[NAG];
  #pragma unroll
  for (int i = 0; i < NAG; ++i) {
    const int c = tid + 512 * i;
    srcA[i] = (c >> 3) * K + ((c ^ (c >> 3)) & 7) * 16;
    dstA[i] = c * 16;
  }
  const int kcs = tid >> 5, js = tid & 31;
  const size_t srcB = (size_t)kcs * N * 4 + 4 * ((4 * js) ^ ((kcs & 1) << 4));
  const int dstB = BOFF + kcs * 512 + js * 16;

  auto stage = [&](int tt) {
    if (tt >= NT) return;
    signed char* dA = lds + (tt & 1) * BUFSZ;
    const signed char* sA = Abase + tt * 128;
    #pragma unroll
    for (int i = 0; i < NAG; ++i) GLDS16(sA + srcA[i], dA + dstA[i]);
    if (wv < 4)
      GLDS16(Wpb + (size_t)tt * (N * 32) + srcB, dA + dstB);
  };

  i32x4_t acc[4][NPL];
  #pragma unroll
  for (int m = 0; m < 4; ++m)
    #pragma unroll
    for (int n = 0; n < NPL; ++n) acc[m][n] = (i32x4_t){0, 0, 0, 0};

  // prologue
  stage(0); stage(1);
  if constexpr (BM == 256) asm volatile("s_waitcnt vmcnt(4)" ::: "memory");
  else                     asm volatile("s_waitcnt vmcnt(2)" ::: "memory");
  __builtin_amdgcn_s_barrier();

  for (int t = 0; t < NT; ++t) {
    const signed char* bufb = lds + (t & 1) * BUFSZ;
    const signed char* pa0 = bufb + aoff0;
    const signed char* pa1 = bufb + aoff1;

    unsigned int bp[2][NPL];
    #pragma unroll
    for (int ks = 0; ks < 2; ++ks)
      #pragma unroll
      for (int np = 0; np < NPL; ++np)
        bp[ks][np] = *(const unsigned int*)(bufb + be[np] + ks * 2048);

    __builtin_amdgcn_s_setprio(1);
    #pragma unroll
    for (int ks = 0; ks < 2; ++ks) {
      i32x4_t bu[NPL];
      #pragma unroll
      for (int np = 0; np < NPL; ++np)
        #pragma unroll
        for (int j = 0; j < 4; ++j)
          bu[np][j] = (int)((bp[ks][np] >> (2 * j)) & 0x03030303u);
      const signed char* pa = ks ? pa1 : pa0;
      #pragma unroll
      for (int m = 0; m < 4; ++m) {
        const i32x4_t af = *(const i32x4_t*)(pa + m * 2048);
        #pragma unroll
        for (int np = 0; np < NPL; ++np)
          acc[m][np] = __builtin_amdgcn_mfma_i32_16x16x64_i8(
              af, bu[np], acc[m][np], 0, 0, 0);
      }
    }
    __builtin_amdgcn_s_setprio(0);

    asm volatile("s_waitcnt lgkmcnt(0)" ::: "memory");
    __builtin_amdgcn_s_barrier();
    stage(t + 2);
    if (t + 2 < NT) {
      if constexpr (BM == 256) asm volatile("s_waitcnt vmcnt(4)" ::: "memory");
      else                     asm volatile("s_waitcnt vmcnt(2)" ::: "memory");
    } else {
      asm volatile("s_waitcnt vmcnt(0)" ::: "memory");
    }
    __builtin_amdgcn_s_barrier();
  }

  // -------- epilogue: undo weight bias, scale, bias, fast tanh, store -------
  const float invw = wsc[widx * 2 + 1];
  const int row0 = bm * BM + wr * 64;
  const int col0 = bn * 128 + wc * PC;
  #pragma unroll
  for (int m = 0; m < 4; ++m) {
    #pragma unroll
    for (int r = 0; r < 4; ++r) {
      const int gb = row0 + m * 16 + g * 4 + r;
      const float fa = inv_sa[gb] * invw;
      const int sr = rsum[gb];
      #pragma unroll
      for (int np = 0; np < NPL; ++np) {
        const int go = col0 + np * 16 + rl;
        const float v = (float)(acc[m][np][r] - sr) * fa + bias[go];
        if constexpr (TANH) {
          const float e2 = __expf(2.f * v);
          const float th = 1.f - 2.f * __builtin_amdgcn_rcpf(e2 + 1.f);
          const float q = fminf(fmaxf(rintf(th * 32767.f), -32767.f), 32767.f);
          ((short*)outv)[(size_t)gb * N + go] = (short)q;
        } else {
          ((float*)outv)[(size_t)gb * N + go] = v;
        }
      }
    }
  }
}

// ---------------- driver ----------------------------------------------------
extern "C" void kernel_launch(void* const* d_in, const int* in_sizes, int n_in,
                              void* d_out, int out_size, void* d_ws, size_t ws_size,
                              hipStream_t stream)
{
  const float* x  = (const float*)d_in[0];
  const float* w1 = (const float*)d_in[1]; const float* b1 = (const float*)d_in[2];
  const float* w2 = (const float*)d_in[3]; const float* b2 = (const float*)d_in[4];
  const float* w3 = (const float*)d_in[5]; const float* b3 = (const float*)d_in[6];
  const float* w4 = (const float*)d_in[7]; const float* b4 = (const float*)d_in[8];
  float* out = (float*)d_out;

  constexpr int B = 8192, DIN = 1024, H = 4096, DOUT = 1024;
  char* ws = (char*)d_ws;
  size_t off = 0;
  short*        hbuf = (short*)(ws + off);        off += (size_t)B * H * 2;   // 64 MB
  signed char*  xq   = (signed char*)(ws + off);  off += (size_t)B * H;
  unsigned int* wp1  = (unsigned int*)(ws + off); off += (size_t)(DIN / 16) * H * 4;
  unsigned int* wp2  = (unsigned int*)(ws + off); off += (size_t)(H / 16) * H * 4;
  unsigned int* wp3  = (unsigned int*)(ws + off); off += (size_t)(H / 16) * H * 4;
  unsigned int* wp4  = (unsigned int*)(ws + off); off += (size_t)(H / 16) * DOUT * 4;
  float*        inv_sa = (float*)(ws + off);      off += (size_t)B * 4;
  int*          rsum = (int*)(ws + off);          off += (size_t)B * 4;
  double*       part = (double*)(ws + off);       off += 1280 * 8;
  float*        wsc  = (float*)(ws + off);        off += 64;

  // weight prep: 3 launches for all four tensors
  absmean4_part_k<<<1280, 256, 0, stream>>>(w1, w2, w3, w4, part);
  absmean4_fin_k<<<1, 256, 0, stream>>>(part, wsc);
  quant_w_pack4_k<<<10240, 256, 0, stream>>>(w1, w2, w3, w4,
                                             wp1, wp2, wp3, wp4, wsc);

  // layer 1: K=DIN=1024, N=H (fp32 input path)
  act_quant_k<DIN, false><<<B, 256, 0, stream>>>(x, (unsigned int*)xq, inv_sa, rsum);
  gemm2p<256, DIN, H, true><<<dim3(H / 128, B / 256), 512, 0, stream>>>(
      xq, wp1, inv_sa, rsum, wsc, 0, b1, hbuf);

  // layer 2: K=H, N=H (q15 h path)
  act_quant_k<H, true><<<B, 256, 0, stream>>>(hbuf, (unsigned int*)xq, inv_sa, rsum);
  gemm2p<256, H, H, true><<<dim3(H / 128, B / 256), 512, 0, stream>>>(
      xq, wp2, inv_sa, rsum, wsc, 1, b2, hbuf);

  // layer 3: K=H, N=H
  act_quant_k<H, true><<<B, 256, 0, stream>>>(hbuf, (unsigned int*)xq, inv_sa, rsum);
  gemm2p<256, H, H, true><<<dim3(H / 128, B / 256), 512, 0, stream>>>(
      xq, wp3, inv_sa, rsum, wsc, 2, b3, hbuf);

  // layer 4: K=H, N=DOUT, no tanh — BM=128, fp32 out
  act_quant_k<H, true><<<B, 256, 0, stream>>>(hbuf, (unsigned int*)xq, inv_sa, rsum);
  gemm2p<128, H, DOUT, false><<<dim3(DOUT / 128, B / 128), 512, 0, stream>>>(
      xq, wp4, inv_sa, rsum, wsc, 3, b4, out);
}